// Round 4
// baseline (788.794 us; speedup 1.0000x reference)
//
#include <hip/hip_runtime.h>
#include <hip/hip_bf16.h>
#include <math.h>

#define S_LEN 2048
#define D_DIM 2048
#define NH 32
#define HD 64
#define CS 256
#define NCH 8

typedef __attribute__((ext_vector_type(8))) short bf16x8;
typedef __attribute__((ext_vector_type(4))) float f32x4;

__device__ __forceinline__ unsigned short f2bf(float f) {
  unsigned int u = __builtin_bit_cast(unsigned int, f);
  unsigned int r = (u + 0x7fffu + ((u >> 16) & 1u)) >> 16;
  return (unsigned short)r;
}
__device__ __forceinline__ float bf2f(unsigned short b) {
  unsigned int u = ((unsigned int)b) << 16;
  return __builtin_bit_cast(float, u);
}

__device__ __forceinline__ void gload16(const void* gp, void* lp) {
  __builtin_amdgcn_global_load_lds(
      (const __attribute__((address_space(1))) unsigned int*)gp,
      (__attribute__((address_space(3))) unsigned int*)lp, 16, 0, 0);
}

// ---------------------------------------------------------------------------
// bf16 MFMA GEMM: C(MxN fp32) = sum_p A_p(MxK bf16) @ B_p^T(NxK bf16).
// 128x128 tile, BK=64, 4 waves (each 64x64), global_load_lds + XOR swizzle.
// ---------------------------------------------------------------------------
struct G3 {
  const unsigned short* A[3];
  const unsigned short* B[3];
  int np;
};

__global__ __launch_bounds__(256) void gemm_bt(G3 g, float* __restrict__ C,
                                               int M, int N, int K) {
  __shared__ __align__(16) unsigned short Als[128 * 64];
  __shared__ __align__(16) unsigned short Bls[128 * 64];
  const int tid = threadIdx.x;
  const int wid = tid >> 6, lane = tid & 63;
  const int l15 = lane & 15, l4 = lane >> 4;
  const int wr = wid >> 1, wc = wid & 1;
  const int nbx = N >> 7;
  int bid = blockIdx.x;
  const int nwg = gridDim.x;
  if ((nwg & 7) == 0) {  // bijective XCD swizzle
    int q = nwg >> 3;
    bid = (bid & 7) * q + (bid >> 3);
  }
  const int row0 = (bid / nbx) << 7;
  const int col0 = (bid % nbx) << 7;

  f32x4 acc[4][4];
#pragma unroll
  for (int m = 0; m < 4; ++m)
#pragma unroll
    for (int n = 0; n < 4; ++n) acc[m][n] = (f32x4){0.f, 0.f, 0.f, 0.f};

  for (int p = 0; p < g.np; ++p) {
    const unsigned short* Ap = g.A[p];
    const unsigned short* Bp = g.B[p];
    for (int kt = 0; kt < K; kt += 64) {
      __syncthreads();
#pragma unroll
      for (int i = 0; i < 4; ++i) {
        const int Lb = i * 4096 + wid * 1024;
        const int L = Lb + lane * 16;
        const int row = L >> 7;
        const int s = (L >> 4) & 7;
        const int cofs = (s ^ (row & 7)) << 3;
        gload16(Ap + (size_t)(row0 + row) * K + kt + cofs, (char*)Als + Lb);
        gload16(Bp + (size_t)(col0 + row) * K + kt + cofs, (char*)Bls + Lb);
      }
      asm volatile("s_waitcnt vmcnt(0)" ::: "memory");
      __syncthreads();
#pragma unroll
      for (int ks = 0; ks < 2; ++ks) {
        bf16x8 af[4], bfr[4];
#pragma unroll
        for (int m = 0; m < 4; ++m) {
          int row = wr * 64 + m * 16 + l15;
          int s = (ks * 4 + l4) ^ (row & 7);
          af[m] = *reinterpret_cast<const bf16x8*>(&Als[row * 64 + s * 8]);
        }
#pragma unroll
        for (int n = 0; n < 4; ++n) {
          int col = wc * 64 + n * 16 + l15;
          int s = (ks * 4 + l4) ^ (col & 7);
          bfr[n] = *reinterpret_cast<const bf16x8*>(&Bls[col * 64 + s * 8]);
        }
#pragma unroll
        for (int m = 0; m < 4; ++m)
#pragma unroll
          for (int n = 0; n < 4; ++n)
            acc[m][n] = __builtin_amdgcn_mfma_f32_16x16x32_bf16(af[m], bfr[n], acc[m][n], 0, 0, 0);
      }
    }
  }

#pragma unroll
  for (int m = 0; m < 4; ++m)
#pragma unroll
    for (int n = 0; n < 4; ++n)
#pragma unroll
      for (int r = 0; r < 4; ++r)
        C[(size_t)(row0 + wr * 64 + m * 16 + l4 * 4 + r) * N + col0 + wc * 64 + n * 16 + l15] =
            acc[m][n][r];
}

// ---------------------------------------------------------------------------
// fp32 SGEMM (kept only for W' = Wg1 @ Wg2, K=64).
// ---------------------------------------------------------------------------
__global__ __launch_bounds__(256) void sgemm_f32(const float* __restrict__ A,
                                                 const float* __restrict__ B,
                                                 float* __restrict__ C,
                                                 int M, int N, int K) {
  __shared__ float As[8][128];
  __shared__ float Bs[8][128];
  const int tid = threadIdx.x;
  const int row0 = blockIdx.y * 128;
  const int col0 = blockIdx.x * 128;
  const int tm = (tid / 16) * 8;
  const int tn = (tid % 16) * 8;
  const int arow = tid >> 1;
  const int acol = (tid & 1) * 4;
  const int brow = tid >> 5;
  const int bcol = (tid & 31) * 4;

  float acc[8][8];
#pragma unroll
  for (int i = 0; i < 8; ++i)
#pragma unroll
    for (int j = 0; j < 8; ++j) acc[i][j] = 0.f;

  for (int k0 = 0; k0 < K; k0 += 8) {
    float4 av = make_float4(0.f, 0.f, 0.f, 0.f);
    if (row0 + arow < M) {
      int kb = k0 + acol;
      av = *reinterpret_cast<const float4*>(&A[(size_t)(row0 + arow) * K + kb]);
    }
    As[acol + 0][arow] = av.x;
    As[acol + 1][arow] = av.y;
    As[acol + 2][arow] = av.z;
    As[acol + 3][arow] = av.w;
    float4 bv = make_float4(0.f, 0.f, 0.f, 0.f);
    if (k0 + brow < K) {
      bv = *reinterpret_cast<const float4*>(&B[(size_t)(k0 + brow) * N + col0 + bcol]);
    }
    *reinterpret_cast<float4*>(&Bs[brow][bcol]) = bv;
    __syncthreads();
#pragma unroll
    for (int kk = 0; kk < 8; ++kk) {
      float a[8], b[8];
      *reinterpret_cast<float4*>(&a[0]) = *reinterpret_cast<const float4*>(&As[kk][tm]);
      *reinterpret_cast<float4*>(&a[4]) = *reinterpret_cast<const float4*>(&As[kk][tm + 4]);
      *reinterpret_cast<float4*>(&b[0]) = *reinterpret_cast<const float4*>(&Bs[kk][tn]);
      *reinterpret_cast<float4*>(&b[4]) = *reinterpret_cast<const float4*>(&Bs[kk][tn + 4]);
#pragma unroll
      for (int i = 0; i < 8; ++i)
#pragma unroll
        for (int j = 0; j < 8; ++j) acc[i][j] = fmaf(a[i], b[j], acc[i][j]);
    }
    __syncthreads();
  }
#pragma unroll
  for (int i = 0; i < 8; ++i) {
    int r = row0 + tm + i;
    if (r < M) {
#pragma unroll
      for (int j = 0; j < 8; ++j) {
        int c = col0 + tn + j;
        if (c < N) C[(size_t)r * N + c] = acc[i][j];
      }
    }
  }
}

// ---------------------------------------------------------------------------
// x fp32 -> xh, xl bf16 (hi/lo split), same layout.
// ---------------------------------------------------------------------------
__global__ __launch_bounds__(256) void repack_x_hl(const float* __restrict__ x,
                                                   unsigned short* __restrict__ xh,
                                                   unsigned short* __restrict__ xl) {
  int i = (blockIdx.x * 256 + threadIdx.x) * 4;
  float4 v = *reinterpret_cast<const float4*>(&x[i]);
  float f[4] = {v.x, v.y, v.z, v.w};
  unsigned short h[4], l[4];
#pragma unroll
  for (int j = 0; j < 4; ++j) {
    h[j] = f2bf(f[j]);
    l[j] = f2bf(f[j] - bf2f(h[j]));
  }
  *reinterpret_cast<ushort4*>(&xh[i]) = make_ushort4(h[0], h[1], h[2], h[3]);
  *reinterpret_cast<ushort4*>(&xl[i]) = make_ushort4(l[0], l[1], l[2], l[3]);
}

// ---------------------------------------------------------------------------
// W (rows x cols, fp32) -> W^T bf16 hi (and optional lo), (cols x rows).
// ---------------------------------------------------------------------------
__global__ __launch_bounds__(256) void repack_T(const float* __restrict__ W,
                                                unsigned short* __restrict__ hiT,
                                                unsigned short* __restrict__ loT,
                                                int rows, int cols, int has_lo) {
  __shared__ float t[64][65];
  const int k0 = blockIdx.y * 64, n0 = blockIdx.x * 64;
  const int tid = threadIdx.x;
  const int c = tid & 63, rr = tid >> 6;
#pragma unroll
  for (int r = 0; r < 16; ++r) {
    int kr = r * 4 + rr;
    t[kr][c] = W[(size_t)(k0 + kr) * cols + n0 + c];
  }
  __syncthreads();
#pragma unroll
  for (int r = 0; r < 16; ++r) {
    int n = r * 4 + rr;
    float f = t[c][n];
    unsigned short hb = f2bf(f);
    hiT[(size_t)(n0 + n) * rows + k0 + c] = hb;
    if (has_lo) loT[(size_t)(n0 + n) * rows + k0 + c] = f2bf(f - bf2f(hb));
  }
}

// ---------------------------------------------------------------------------
// RoPE applied in-place to q and k.
// ---------------------------------------------------------------------------
__global__ __launch_bounds__(256) void rope_qk(float* __restrict__ q, float* __restrict__ kk) {
  int idx = blockIdx.x * 256 + threadIdx.x;
  if (idx >= S_LEN * NH * (HD / 2)) return;
  int d = idx & 31;
  int sh = idx >> 5;
  int s = sh >> 5;
  float inv = 1.0f / powf(10000.0f, (float)d * (1.0f / 32.0f));
  float fr = (float)s * inv;
  float c = cosf(fr), sn = sinf(fr);
  size_t base = (size_t)sh * HD + d;
  float q1 = q[base], q2 = q[base + 32];
  q[base] = q1 * c - q2 * sn;
  q[base + 32] = q2 * c + q1 * sn;
  float k1 = kk[base], k2 = kk[base + 32];
  kk[base] = k1 * c - k2 * sn;
  kk[base + 32] = k2 * c + k1 * sn;
}

// ---------------------------------------------------------------------------
// Chunk means of k.
// ---------------------------------------------------------------------------
__global__ __launch_bounds__(256) void chunk_mean(const float* __restrict__ k,
                                                  float* __restrict__ kg) {
  int idx = blockIdx.x * 256 + threadIdx.x;
  if (idx >= NCH * NH * HD) return;
  int c = idx / (NH * HD);
  int hd = idx % (NH * HD);
  float sum = 0.f;
  for (int t = 0; t < CS; ++t) sum += k[(size_t)(c * CS + t) * (NH * HD) + hd];
  kg[idx] = sum * (1.0f / CS);
}

// ---------------------------------------------------------------------------
// Gate + top-3-past chunk selection (fp32).
// ---------------------------------------------------------------------------
__global__ __launch_bounds__(256) void gate_topk(const float* __restrict__ q,
                                                 const float* __restrict__ kg,
                                                 int* __restrict__ amask) {
  int wid = threadIdx.x >> 6;
  int lane = threadIdx.x & 63;
  int s = blockIdx.x * 4 + wid;
  int h = blockIdx.y;
  int myc = s >> 8;
  float qd = q[((size_t)s * NH + h) * HD + lane];
  float g[NCH];
#pragma unroll
  for (int c = 0; c < NCH; ++c) {
    float p = qd * kg[((size_t)c * NH + h) * HD + lane];
#pragma unroll
    for (int off = 32; off; off >>= 1) p += __shfl_xor(p, off);
    g[c] = p;
  }
  int chosen = 0;
#pragma unroll
  for (int pick = 0; pick < 3; ++pick) {
    float best = -INFINITY;
    int bi = -1;
#pragma unroll
    for (int c = 0; c < NCH; ++c) {
      if (c < myc && !((chosen >> c) & 1) && g[c] > best) {
        best = g[c];
        bi = c;
      }
    }
    if (bi >= 0) chosen |= (1 << bi);
  }
  int mask = chosen | (1 << myc);
  if (lane == 0) amask[h * S_LEN + s] = mask;
}

// ---------------------------------------------------------------------------
// Repack k fp32 [s][h][d] -> kh/kl bf16 hi/lo [h][s][d]
// ---------------------------------------------------------------------------
__global__ __launch_bounds__(256) void repack_k(const float* __restrict__ k,
                                                unsigned short* __restrict__ kh,
                                                unsigned short* __restrict__ kl) {
  int t = blockIdx.x * 256 + threadIdx.x;
  int d4 = (t & 15) * 4;
  int s = (t >> 4) & (S_LEN - 1);
  int h = t >> 15;
  float4 v = *reinterpret_cast<const float4*>(&k[(((size_t)s * NH + h) * HD + d4)]);
  size_t oi = ((size_t)h * S_LEN + s) * HD + d4;
  float f[4] = {v.x, v.y, v.z, v.w};
  unsigned short hi[4], lo[4];
#pragma unroll
  for (int j = 0; j < 4; ++j) {
    hi[j] = f2bf(f[j]);
    lo[j] = f2bf(f[j] - bf2f(hi[j]));
  }
  *reinterpret_cast<ushort4*>(&kh[oi]) = make_ushort4(hi[0], hi[1], hi[2], hi[3]);
  *reinterpret_cast<ushort4*>(&kl[oi]) = make_ushort4(lo[0], lo[1], lo[2], lo[3]);
}

// ---------------------------------------------------------------------------
// Repack v fp32 [s][h][d] -> vT bf16 [h][d][s]  (LDS transpose)
// ---------------------------------------------------------------------------
__global__ __launch_bounds__(256) void repack_vT(const float* __restrict__ v,
                                                 unsigned short* __restrict__ vT) {
  __shared__ float tile[64][65];
  const int h = blockIdx.y;
  const int sb = blockIdx.x * 64;
  const int tid = threadIdx.x;
#pragma unroll
  for (int r = 0; r < 16; ++r) {
    int row = r * 4 + (tid >> 6);
    int d = tid & 63;
    tile[row][d] = v[((size_t)(sb + row) * NH + h) * HD + d];
  }
  __syncthreads();
#pragma unroll
  for (int r = 0; r < 16; ++r) {
    int d = r * 4 + (tid >> 6);
    int si = tid & 63;
    vT[((size_t)h * HD + d) * S_LEN + sb + si] = f2bf(tile[si][d]);
  }
}

// ---------------------------------------------------------------------------
// MFMA flash attention over selected chunks.
// ---------------------------------------------------------------------------
__global__ __launch_bounds__(256) void attn_mfma(const float* __restrict__ q,
                                                 const unsigned short* __restrict__ kh,
                                                 const unsigned short* __restrict__ kl,
                                                 const unsigned short* __restrict__ vT,
                                                 const int* __restrict__ amask,
                                                 float* __restrict__ o) {
  const int h = blockIdx.y;
  const int wid = threadIdx.x >> 6;
  const int lane = threadIdx.x & 63;
  const int qr = lane & 15;
  const int g = lane >> 4;
  const int s0 = blockIdx.x * 64 + wid * 16;
  const int myS = s0 + qr;
  const int myc = s0 >> 8;

  const float* qrow = q + ((size_t)myS * NH + h) * HD;
  bf16x8 qhf[2], qlf[2];
#pragma unroll
  for (int hf = 0; hf < 2; ++hf) {
#pragma unroll
    for (int j = 0; j < 8; ++j) {
      float f = qrow[hf * 32 + g * 8 + j];
      unsigned short hb = f2bf(f);
      qhf[hf][j] = (short)hb;
      qlf[hf][j] = (short)f2bf(f - bf2f(hb));
    }
  }

  int mymask = amask[h * S_LEN + myS];
  int wmask = mymask;
  wmask |= __shfl_xor(wmask, 1);
  wmask |= __shfl_xor(wmask, 2);
  wmask |= __shfl_xor(wmask, 4);
  wmask |= __shfl_xor(wmask, 8);

  float m = -1e30f, lsum = 0.f;
  f32x4 accv[4];
#pragma unroll
  for (int i = 0; i < 4; ++i) accv[i] = (f32x4){0.f, 0.f, 0.f, 0.f};

  const int ktm = (s0 & (CS - 1)) >> 6;
  const unsigned short* khh = kh + (size_t)h * S_LEN * HD;
  const unsigned short* khl = kl + (size_t)h * S_LEN * HD;
  const unsigned short* vth = vT + (size_t)h * HD * S_LEN;

  for (int c = 0; c <= myc; ++c) {
    if (!((wmask >> c) & 1)) continue;
    const bool lane_on = (mymask >> c) & 1;
    const int nkt = (c == myc) ? (ktm + 1) : 4;
    for (int kt = 0; kt < nkt; ++kt) {
      const int t0 = c * CS + kt * 64;
      const bool diag = (c == myc) && (kt == ktm);

      float p[16];
      float mt = -1e30f;
#pragma unroll
      for (int st = 0; st < 4; ++st) {
        const size_t krow = (size_t)(t0 + st * 16 + qr) * HD + g * 8;
        bf16x8 ah0 = *reinterpret_cast<const bf16x8*>(khh + krow);
        bf16x8 ah1 = *reinterpret_cast<const bf16x8*>(khh + krow + 32);
        bf16x8 al0 = *reinterpret_cast<const bf16x8*>(khl + krow);
        bf16x8 al1 = *reinterpret_cast<const bf16x8*>(khl + krow + 32);
        f32x4 d = (f32x4){0.f, 0.f, 0.f, 0.f};
        d = __builtin_amdgcn_mfma_f32_16x16x32_bf16(ah0, qhf[0], d, 0, 0, 0);
        d = __builtin_amdgcn_mfma_f32_16x16x32_bf16(ah1, qhf[1], d, 0, 0, 0);
        d = __builtin_amdgcn_mfma_f32_16x16x32_bf16(ah0, qlf[0], d, 0, 0, 0);
        d = __builtin_amdgcn_mfma_f32_16x16x32_bf16(ah1, qlf[1], d, 0, 0, 0);
        d = __builtin_amdgcn_mfma_f32_16x16x32_bf16(al0, qhf[0], d, 0, 0, 0);
        d = __builtin_amdgcn_mfma_f32_16x16x32_bf16(al1, qhf[1], d, 0, 0, 0);
#pragma unroll
        for (int r = 0; r < 4; ++r) {
          bool ok = lane_on && (!diag || (t0 + st * 16 + 4 * g + r <= myS));
          float sv = ok ? d[r] * 0.125f : -1e30f;
          p[st * 4 + r] = sv;
          mt = fmaxf(mt, sv);
        }
      }
      mt = fmaxf(mt, __shfl_xor(mt, 16));
      mt = fmaxf(mt, __shfl_xor(mt, 32));
      const float mnew = fmaxf(m, mt);
      const float corr = __expf(m - mnew);
      float ps = 0.f;
#pragma unroll
      for (int i = 0; i < 16; ++i) {
        float pv = (p[i] > -1e29f) ? __expf(p[i] - mnew) : 0.f;
        p[i] = pv;
        ps += pv;
      }
      ps += __shfl_xor(ps, 16);
      ps += __shfl_xor(ps, 32);
      lsum = lsum * corr + ps;
      m = mnew;
#pragma unroll
      for (int i = 0; i < 4; ++i) accv[i] *= corr;

      unsigned int pk[4][2];
#pragma unroll
      for (int t = 0; t < 4; ++t) {
        pk[t][0] = (unsigned int)f2bf(p[4 * t + 0]) | ((unsigned int)f2bf(p[4 * t + 1]) << 16);
        pk[t][1] = (unsigned int)f2bf(p[4 * t + 2]) | ((unsigned int)f2bf(p[4 * t + 3]) << 16);
      }
      const int srcA = qr + 32 * (g & 1);
      const int srcB = srcA + 16;
      const bool tsel = (g >> 1) != 0;
#pragma unroll
      for (int hf = 0; hf < 2; ++hf) {
        unsigned int a0 = (unsigned int)__shfl((int)pk[2 * hf][0], srcA);
        unsigned int b0 = (unsigned int)__shfl((int)pk[2 * hf + 1][0], srcA);
        unsigned int a1 = (unsigned int)__shfl((int)pk[2 * hf][1], srcA);
        unsigned int b1 = (unsigned int)__shfl((int)pk[2 * hf + 1][1], srcA);
        unsigned int a2 = (unsigned int)__shfl((int)pk[2 * hf][0], srcB);
        unsigned int b2 = (unsigned int)__shfl((int)pk[2 * hf + 1][0], srcB);
        unsigned int a3 = (unsigned int)__shfl((int)pk[2 * hf][1], srcB);
        unsigned int b3 = (unsigned int)__shfl((int)pk[2 * hf + 1][1], srcB);
        union { unsigned int u[4]; bf16x8 v; } pf;
        pf.u[0] = tsel ? b0 : a0;
        pf.u[1] = tsel ? b1 : a1;
        pf.u[2] = tsel ? b2 : a2;
        pf.u[3] = tsel ? b3 : a3;
#pragma unroll
        for (int mhd = 0; mhd < 4; ++mhd) {
          const bf16x8 vf = *reinterpret_cast<const bf16x8*>(
              vth + (size_t)(mhd * 16 + qr) * S_LEN + t0 + hf * 32 + g * 8);
          accv[mhd] = __builtin_amdgcn_mfma_f32_16x16x32_bf16(vf, pf.v, accv[mhd], 0, 0, 0);
        }
      }
    }
  }

  const float inv = 1.0f / lsum;
  float* orow = o + ((size_t)myS * NH + h) * HD;
#pragma unroll
  for (int mhd = 0; mhd < 4; ++mhd) {
    f32x4 r = accv[mhd];
    r *= inv;
    *reinterpret_cast<f32x4*>(orow + mhd * 16 + 4 * g) = r;
  }
}

// ---------------------------------------------------------------------------
// RMS-norm + sigmoid gate; emits bf16 for the out-proj A-operand.
// ---------------------------------------------------------------------------
__global__ __launch_bounds__(256) void postproc(const float* __restrict__ o,
                                                const float* __restrict__ g,
                                                const float* __restrict__ w,
                                                unsigned short* __restrict__ o2h) {
  int idx = blockIdx.x * 256 + threadIdx.x;
  int lane = threadIdx.x & 63;
  float val = o[idx];
  float ss = val * val;
#pragma unroll
  for (int off = 32; off; off >>= 1) ss += __shfl_xor(ss, off);
  float r = rsqrtf(ss * (1.0f / HD) + 1e-6f);
  float gv = g[idx];
  float sig = 1.0f / (1.0f + expf(-gv));
  o2h[idx] = f2bf(val * r * w[lane] * sig);
}

// ---------------------------------------------------------------------------
extern "C" void kernel_launch(void* const* d_in, const int* in_sizes, int n_in,
                              void* d_out, int out_size, void* d_ws, size_t ws_size,
                              hipStream_t stream) {
  const float* x   = (const float*)d_in[0];
  const float* Wq  = (const float*)d_in[1];
  const float* Wk  = (const float*)d_in[2];
  const float* Wv  = (const float*)d_in[3];
  const float* Wo  = (const float*)d_in[4];
  const float* Wg1 = (const float*)d_in[5];
  const float* Wg2 = (const float*)d_in[6];
  const float* onw = (const float*)d_in[7];
  float* out = (float*)d_out;

  const size_t BIG = (size_t)S_LEN * D_DIM;  // 4M elements
  float* q  = (float*)d_ws;
  float* k  = q + BIG;
  float* v  = k + BIG;
  float* o  = v + BIG;
  float* kg = o + BIG;                        // NCH*NH*HD
  int* amask = (int*)(kg + NCH * NH * HD);    // NH*S
  unsigned short* xh  = (unsigned short*)(amask + NH * S_LEN);
  unsigned short* xl  = xh + BIG;
  unsigned short* whT = xl + BIG;
  unsigned short* wlT = whT + BIG;
  unsigned short* kh  = wlT + BIG;
  unsigned short* kl  = kh + BIG;
  unsigned short* vT  = kl + BIG;
  unsigned short* o2h = vT + BIG;

  const dim3 gT(32, 32);
  // Split x into hi/lo bf16
  repack_x_hl<<<(int)(BIG / 4 / 256), 256, 0, stream>>>(x, xh, xl);

  // Q = x@Wq (3-pass hi/lo)
  repack_T<<<gT, 256, 0, stream>>>(Wq, whT, wlT, D_DIM, D_DIM, 1);
  {
    G3 g3{{xh, xh, xl}, {whT, wlT, whT}, 3};
    gemm_bt<<<256, 256, 0, stream>>>(g3, q, S_LEN, D_DIM, D_DIM);
  }
  // K = x@Wk (3-pass hi/lo)
  repack_T<<<gT, 256, 0, stream>>>(Wk, whT, wlT, D_DIM, D_DIM, 1);
  {
    G3 g3{{xh, xh, xl}, {whT, wlT, whT}, 3};
    gemm_bt<<<256, 256, 0, stream>>>(g3, k, S_LEN, D_DIM, D_DIM);
  }
  // V = x@Wv (1-pass bf16)
  repack_T<<<gT, 256, 0, stream>>>(Wv, whT, nullptr, D_DIM, D_DIM, 0);
  {
    G3 g3{{xh, xh, xh}, {whT, whT, whT}, 1};
    gemm_bt<<<256, 256, 0, stream>>>(g3, v, S_LEN, D_DIM, D_DIM);
  }
  // RoPE
  rope_qk<<<S_LEN * NH * (HD / 2) / 256, 256, 0, stream>>>(q, k);
  // Chunk means + gating (fp32)
  chunk_mean<<<(NCH * NH * HD + 255) / 256, 256, 0, stream>>>(k, kg);
  gate_topk<<<dim3(S_LEN / 4, NH), 256, 0, stream>>>(q, kg, amask);
  // Repack for MFMA attention
  repack_k<<<(int)(BIG / 4 / 256), 256, 0, stream>>>(k, kh, kl);
  repack_vT<<<dim3(S_LEN / 64, NH), 256, 0, stream>>>(v, vT);
  // W' = Wg1 @ Wg2 (fp32, K=64) into o; then repack to bf16 T
  sgemm_f32<<<dim3(16, 16), 256, 0, stream>>>(Wg1, Wg2, o, D_DIM, D_DIM, HD);
  repack_T<<<gT, 256, 0, stream>>>(o, whT, nullptr, D_DIM, D_DIM, 0);
  // Attention (overwrites o)
  attn_mfma<<<dim3(S_LEN / 64, NH), 256, 0, stream>>>(q, kh, kl, vT, amask, o);
  // g = x @ W' (1-pass bf16) into k buffer
  {
    G3 g3{{xh, xh, xh}, {whT, whT, whT}, 1};
    gemm_bt<<<256, 256, 0, stream>>>(g3, k, S_LEN, D_DIM, D_DIM);
  }
  // RMS-norm + sigmoid gate -> bf16
  postproc<<<(int)(BIG / 256), 256, 0, stream>>>(o, k, onw, o2h);
  // out = o2 @ Wo (1-pass bf16)
  repack_T<<<gT, 256, 0, stream>>>(Wo, whT, nullptr, D_DIM, D_DIM, 0);
  {
    G3 g3{{o2h, o2h, o2h}, {whT, whT, whT}, 1};
    gemm_bt<<<256, 256, 0, stream>>>(g3, out, S_LEN, D_DIM, D_DIM);
  }
}

// Round 5
// 776.925 us; speedup vs baseline: 1.0153x; 1.0153x over previous
//
#include <hip/hip_runtime.h>
#include <hip/hip_bf16.h>
#include <math.h>

#define S_LEN 2048
#define D_DIM 2048
#define NH 32
#define HD 64
#define CS 256
#define NCH 8

typedef __attribute__((ext_vector_type(8))) short bf16x8;
typedef __attribute__((ext_vector_type(4))) short bf16x4;
typedef __attribute__((ext_vector_type(4))) float f32x4;

__device__ __forceinline__ unsigned short f2bf(float f) {
  unsigned int u = __builtin_bit_cast(unsigned int, f);
  unsigned int r = (u + 0x7fffu + ((u >> 16) & 1u)) >> 16;
  return (unsigned short)r;
}
__device__ __forceinline__ float bf2f(unsigned short b) {
  unsigned int u = ((unsigned int)b) << 16;
  return __builtin_bit_cast(float, u);
}

__device__ __forceinline__ f32x4 mfma16(bf16x4 a, bf16x4 b, f32x4 c) {
#if __has_builtin(__builtin_amdgcn_mfma_f32_16x16x16_bf16)
  return __builtin_amdgcn_mfma_f32_16x16x16_bf16(a, b, c, 0, 0, 0);
#elif __has_builtin(__builtin_amdgcn_mfma_f32_16x16x16bf16_1k)
  return __builtin_amdgcn_mfma_f32_16x16x16bf16_1k(a, b, c, 0, 0, 0);
#else
  asm("v_mfma_f32_16x16x16_bf16 %0, %1, %2, %0" : "+v"(c) : "v"(a), "v"(b));
  return c;
#endif
}

__device__ __forceinline__ void gload16(const void* gp, void* lp) {
  __builtin_amdgcn_global_load_lds(
      (const __attribute__((address_space(1))) unsigned int*)gp,
      (__attribute__((address_space(3))) unsigned int*)lp, 16, 0, 0);
}

// ---------------------------------------------------------------------------
// bf16 MFMA GEMM: C(MxN fp32) = sum_p A_p(MxK bf16) @ B_p^T(NxK bf16).
// ---------------------------------------------------------------------------
struct G3 {
  const unsigned short* A[3];
  const unsigned short* B[3];
  int np;
};

__global__ __launch_bounds__(256) void gemm_bt(G3 g, float* __restrict__ C,
                                               int M, int N, int K) {
  __shared__ __align__(16) unsigned short Als[128 * 64];
  __shared__ __align__(16) unsigned short Bls[128 * 64];
  const int tid = threadIdx.x;
  const int wid = tid >> 6, lane = tid & 63;
  const int l15 = lane & 15, l4 = lane >> 4;
  const int wr = wid >> 1, wc = wid & 1;
  const int nbx = N >> 7;
  int bid = blockIdx.x;
  const int nwg = gridDim.x;
  if ((nwg & 7) == 0) {  // bijective XCD swizzle
    int q = nwg >> 3;
    bid = (bid & 7) * q + (bid >> 3);
  }
  const int row0 = (bid / nbx) << 7;
  const int col0 = (bid % nbx) << 7;

  f32x4 acc[4][4];
#pragma unroll
  for (int m = 0; m < 4; ++m)
#pragma unroll
    for (int n = 0; n < 4; ++n) acc[m][n] = (f32x4){0.f, 0.f, 0.f, 0.f};

  for (int p = 0; p < g.np; ++p) {
    const unsigned short* Ap = g.A[p];
    const unsigned short* Bp = g.B[p];
    for (int kt = 0; kt < K; kt += 64) {
      __syncthreads();
#pragma unroll
      for (int i = 0; i < 4; ++i) {
        const int Lb = i * 4096 + wid * 1024;
        const int L = Lb + lane * 16;
        const int row = L >> 7;
        const int s = (L >> 4) & 7;
        const int cofs = (s ^ (row & 7)) << 3;
        gload16(Ap + (size_t)(row0 + row) * K + kt + cofs, (char*)Als + Lb);
        gload16(Bp + (size_t)(col0 + row) * K + kt + cofs, (char*)Bls + Lb);
      }
      asm volatile("s_waitcnt vmcnt(0)" ::: "memory");
      __syncthreads();
#pragma unroll
      for (int ks = 0; ks < 2; ++ks) {
        bf16x8 af[4], bfr[4];
#pragma unroll
        for (int m = 0; m < 4; ++m) {
          int row = wr * 64 + m * 16 + l15;
          int s = (ks * 4 + l4) ^ (row & 7);
          af[m] = *reinterpret_cast<const bf16x8*>(&Als[row * 64 + s * 8]);
        }
#pragma unroll
        for (int n = 0; n < 4; ++n) {
          int col = wc * 64 + n * 16 + l15;
          int s = (ks * 4 + l4) ^ (col & 7);
          bfr[n] = *reinterpret_cast<const bf16x8*>(&Bls[col * 64 + s * 8]);
        }
#pragma unroll
        for (int m = 0; m < 4; ++m)
#pragma unroll
          for (int n = 0; n < 4; ++n)
            acc[m][n] = __builtin_amdgcn_mfma_f32_16x16x32_bf16(af[m], bfr[n], acc[m][n], 0, 0, 0);
      }
    }
  }

#pragma unroll
  for (int m = 0; m < 4; ++m)
#pragma unroll
    for (int n = 0; n < 4; ++n)
#pragma unroll
      for (int r = 0; r < 4; ++r)
        C[(size_t)(row0 + wr * 64 + m * 16 + l4 * 4 + r) * N + col0 + wc * 64 + n * 16 + l15] =
            acc[m][n][r];
}

// ---------------------------------------------------------------------------
// fp32 SGEMM (kept only for W' = Wg1 @ Wg2, K=64).
// ---------------------------------------------------------------------------
__global__ __launch_bounds__(256) void sgemm_f32(const float* __restrict__ A,
                                                 const float* __restrict__ B,
                                                 float* __restrict__ C,
                                                 int M, int N, int K) {
  __shared__ float As[8][128];
  __shared__ float Bs[8][128];
  const int tid = threadIdx.x;
  const int row0 = blockIdx.y * 128;
  const int col0 = blockIdx.x * 128;
  const int tm = (tid / 16) * 8;
  const int tn = (tid % 16) * 8;
  const int arow = tid >> 1;
  const int acol = (tid & 1) * 4;
  const int brow = tid >> 5;
  const int bcol = (tid & 31) * 4;

  float acc[8][8];
#pragma unroll
  for (int i = 0; i < 8; ++i)
#pragma unroll
    for (int j = 0; j < 8; ++j) acc[i][j] = 0.f;

  for (int k0 = 0; k0 < K; k0 += 8) {
    float4 av = make_float4(0.f, 0.f, 0.f, 0.f);
    if (row0 + arow < M) {
      int kb = k0 + acol;
      av = *reinterpret_cast<const float4*>(&A[(size_t)(row0 + arow) * K + kb]);
    }
    As[acol + 0][arow] = av.x;
    As[acol + 1][arow] = av.y;
    As[acol + 2][arow] = av.z;
    As[acol + 3][arow] = av.w;
    float4 bv = make_float4(0.f, 0.f, 0.f, 0.f);
    if (k0 + brow < K) {
      bv = *reinterpret_cast<const float4*>(&B[(size_t)(k0 + brow) * N + col0 + bcol]);
    }
    *reinterpret_cast<float4*>(&Bs[brow][bcol]) = bv;
    __syncthreads();
#pragma unroll
    for (int kk = 0; kk < 8; ++kk) {
      float a[8], b[8];
      *reinterpret_cast<float4*>(&a[0]) = *reinterpret_cast<const float4*>(&As[kk][tm]);
      *reinterpret_cast<float4*>(&a[4]) = *reinterpret_cast<const float4*>(&As[kk][tm + 4]);
      *reinterpret_cast<float4*>(&b[0]) = *reinterpret_cast<const float4*>(&Bs[kk][tn]);
      *reinterpret_cast<float4*>(&b[4]) = *reinterpret_cast<const float4*>(&Bs[kk][tn + 4]);
#pragma unroll
      for (int i = 0; i < 8; ++i)
#pragma unroll
        for (int j = 0; j < 8; ++j) acc[i][j] = fmaf(a[i], b[j], acc[i][j]);
    }
    __syncthreads();
  }
#pragma unroll
  for (int i = 0; i < 8; ++i) {
    int r = row0 + tm + i;
    if (r < M) {
#pragma unroll
      for (int j = 0; j < 8; ++j) {
        int c = col0 + tn + j;
        if (c < N) C[(size_t)r * N + c] = acc[i][j];
      }
    }
  }
}

// ---------------------------------------------------------------------------
// x fp32 -> xh, xl bf16 (hi/lo split), same layout.
// ---------------------------------------------------------------------------
__global__ __launch_bounds__(256) void repack_x_hl(const float* __restrict__ x,
                                                   unsigned short* __restrict__ xh,
                                                   unsigned short* __restrict__ xl) {
  int i = (blockIdx.x * 256 + threadIdx.x) * 4;
  float4 v = *reinterpret_cast<const float4*>(&x[i]);
  float f[4] = {v.x, v.y, v.z, v.w};
  unsigned short h[4], l[4];
#pragma unroll
  for (int j = 0; j < 4; ++j) {
    h[j] = f2bf(f[j]);
    l[j] = f2bf(f[j] - bf2f(h[j]));
  }
  *reinterpret_cast<ushort4*>(&xh[i]) = make_ushort4(h[0], h[1], h[2], h[3]);
  *reinterpret_cast<ushort4*>(&xl[i]) = make_ushort4(l[0], l[1], l[2], l[3]);
}

// ---------------------------------------------------------------------------
// W (rows x cols, fp32) -> W^T bf16 hi (and optional lo), (cols x rows).
// ---------------------------------------------------------------------------
__global__ __launch_bounds__(256) void repack_T(const float* __restrict__ W,
                                                unsigned short* __restrict__ hiT,
                                                unsigned short* __restrict__ loT,
                                                int rows, int cols, int has_lo) {
  __shared__ float t[64][65];
  const int k0 = blockIdx.y * 64, n0 = blockIdx.x * 64;
  const int tid = threadIdx.x;
  const int c = tid & 63, rr = tid >> 6;
#pragma unroll
  for (int r = 0; r < 16; ++r) {
    int kr = r * 4 + rr;
    t[kr][c] = W[(size_t)(k0 + kr) * cols + n0 + c];
  }
  __syncthreads();
#pragma unroll
  for (int r = 0; r < 16; ++r) {
    int n = r * 4 + rr;
    float f = t[c][n];
    unsigned short hb = f2bf(f);
    hiT[(size_t)(n0 + n) * rows + k0 + c] = hb;
    if (has_lo) loT[(size_t)(n0 + n) * rows + k0 + c] = f2bf(f - bf2f(hb));
  }
}

// ---------------------------------------------------------------------------
// RoPE applied in-place to q and k.
// ---------------------------------------------------------------------------
__global__ __launch_bounds__(256) void rope_qk(float* __restrict__ q, float* __restrict__ kk) {
  int idx = blockIdx.x * 256 + threadIdx.x;
  if (idx >= S_LEN * NH * (HD / 2)) return;
  int d = idx & 31;
  int sh = idx >> 5;
  int s = sh >> 5;
  float inv = 1.0f / powf(10000.0f, (float)d * (1.0f / 32.0f));
  float fr = (float)s * inv;
  float c = cosf(fr), sn = sinf(fr);
  size_t base = (size_t)sh * HD + d;
  float q1 = q[base], q2 = q[base + 32];
  q[base] = q1 * c - q2 * sn;
  q[base + 32] = q2 * c + q1 * sn;
  float k1 = kk[base], k2 = kk[base + 32];
  kk[base] = k1 * c - k2 * sn;
  kk[base + 32] = k2 * c + k1 * sn;
}

// ---------------------------------------------------------------------------
// Chunk means of k.
// ---------------------------------------------------------------------------
__global__ __launch_bounds__(256) void chunk_mean(const float* __restrict__ k,
                                                  float* __restrict__ kg) {
  int idx = blockIdx.x * 256 + threadIdx.x;
  if (idx >= NCH * NH * HD) return;
  int c = idx / (NH * HD);
  int hd = idx % (NH * HD);
  float sum = 0.f;
  for (int t = 0; t < CS; ++t) sum += k[(size_t)(c * CS + t) * (NH * HD) + hd];
  kg[idx] = sum * (1.0f / CS);
}

// ---------------------------------------------------------------------------
// Gate + top-3-past chunk selection (fp32 — selection must stay exact).
// ---------------------------------------------------------------------------
__global__ __launch_bounds__(256) void gate_topk(const float* __restrict__ q,
                                                 const float* __restrict__ kg,
                                                 int* __restrict__ amask) {
  int wid = threadIdx.x >> 6;
  int lane = threadIdx.x & 63;
  int s = blockIdx.x * 4 + wid;
  int h = blockIdx.y;
  int myc = s >> 8;
  float qd = q[((size_t)s * NH + h) * HD + lane];
  float g[NCH];
#pragma unroll
  for (int c = 0; c < NCH; ++c) {
    float p = qd * kg[((size_t)c * NH + h) * HD + lane];
#pragma unroll
    for (int off = 32; off; off >>= 1) p += __shfl_xor(p, off);
    g[c] = p;
  }
  int chosen = 0;
#pragma unroll
  for (int pick = 0; pick < 3; ++pick) {
    float best = -INFINITY;
    int bi = -1;
#pragma unroll
    for (int c = 0; c < NCH; ++c) {
      if (c < myc && !((chosen >> c) & 1) && g[c] > best) {
        best = g[c];
        bi = c;
      }
    }
    if (bi >= 0) chosen |= (1 << bi);
  }
  int mask = chosen | (1 << myc);
  if (lane == 0) amask[h * S_LEN + s] = mask;
}

// ---------------------------------------------------------------------------
// Repack k fp32 [s][h][d] -> kh bf16 [h][s][d]
// ---------------------------------------------------------------------------
__global__ __launch_bounds__(256) void repack_k(const float* __restrict__ k,
                                                unsigned short* __restrict__ kh) {
  int t = blockIdx.x * 256 + threadIdx.x;
  int d4 = (t & 15) * 4;
  int s = (t >> 4) & (S_LEN - 1);
  int h = t >> 15;
  float4 v = *reinterpret_cast<const float4*>(&k[(((size_t)s * NH + h) * HD + d4)]);
  size_t oi = ((size_t)h * S_LEN + s) * HD + d4;
  *reinterpret_cast<ushort4*>(&kh[oi]) =
      make_ushort4(f2bf(v.x), f2bf(v.y), f2bf(v.z), f2bf(v.w));
}

// ---------------------------------------------------------------------------
// Repack v fp32 [s][h][d] -> vT bf16 [h][d][s]  (LDS transpose)
// ---------------------------------------------------------------------------
__global__ __launch_bounds__(256) void repack_vT(const float* __restrict__ v,
                                                 unsigned short* __restrict__ vT) {
  __shared__ float tile[64][65];
  const int h = blockIdx.y;
  const int sb = blockIdx.x * 64;
  const int tid = threadIdx.x;
#pragma unroll
  for (int r = 0; r < 16; ++r) {
    int row = r * 4 + (tid >> 6);
    int d = tid & 63;
    tile[row][d] = v[((size_t)(sb + row) * NH + h) * HD + d];
  }
  __syncthreads();
#pragma unroll
  for (int r = 0; r < 16; ++r) {
    int d = r * 4 + (tid >> 6);
    int si = tid & 63;
    vT[((size_t)h * HD + d) * S_LEN + sb + si] = f2bf(tile[si][d]);
  }
}

// ---------------------------------------------------------------------------
// MFMA flash attention over selected chunks. One 64-lane wave per 16 q-rows
// of one head. S^T = K.Q^T (16x16x32 bf16); the S^T output fragment is
// directly the A-fragment of 16x16x16 PV MFMA -> zero-shuffle PV.
// ---------------------------------------------------------------------------
__global__ __launch_bounds__(64) void attn_mfma(const float* __restrict__ q,
                                                const unsigned short* __restrict__ kh,
                                                const unsigned short* __restrict__ vT,
                                                const int* __restrict__ amask,
                                                float* __restrict__ o) {
  const int h = blockIdx.y;
  const int lane = threadIdx.x;
  const int l15 = lane & 15, g = lane >> 4;
  const int s0 = blockIdx.x * 16;
  const int myS = s0 + l15;
  const int myc = s0 >> 8;

  // Q B-frag (16x16x32): lane holds Q[row=l15][hd=hf*32+g*8+j]
  const float* qrow = q + ((size_t)myS * NH + h) * HD;
  bf16x8 qf[2];
#pragma unroll
  for (int hf = 0; hf < 2; ++hf)
#pragma unroll
    for (int j = 0; j < 8; ++j) qf[hf][j] = (short)f2bf(qrow[hf * 32 + g * 8 + j]);

  int mymask = amask[h * S_LEN + myS];
  int wmask = mymask;
  wmask |= __shfl_xor(wmask, 1);
  wmask |= __shfl_xor(wmask, 2);
  wmask |= __shfl_xor(wmask, 4);
  wmask |= __shfl_xor(wmask, 8);

  float m = -1e30f, lsum = 0.f;
  f32x4 accv[4];
#pragma unroll
  for (int i = 0; i < 4; ++i) accv[i] = (f32x4){0.f, 0.f, 0.f, 0.f};

  const int ktm = (s0 & (CS - 1)) >> 6;
  const unsigned short* khh = kh + (size_t)h * S_LEN * HD;
  const unsigned short* vth = vT + (size_t)h * HD * S_LEN;

  for (int c = 0; c <= myc; ++c) {
    if (!((wmask >> c) & 1)) continue;
    const bool lane_on = (mymask >> c) & 1;
    const int nkt = (c == myc) ? (ktm + 1) : 4;
    for (int kt = 0; kt < nkt; ++kt) {
      const int t0 = c * CS + kt * 64;
      const bool diag = (c == myc) && (kt == ktm);

      // Prefetch V B-frags (16x16x16): V^T[cb*16+l15][t0+st*16+4g .. +3]
      bf16x4 vb[4][4];
#pragma unroll
      for (int st = 0; st < 4; ++st)
#pragma unroll
        for (int cb = 0; cb < 4; ++cb)
          vb[st][cb] = *reinterpret_cast<const bf16x4*>(
              vth + (size_t)(cb * 16 + l15) * S_LEN + t0 + st * 16 + 4 * g);

      // S^T tile: 4 key-subtiles x 2 hd-halves, plain bf16
      float p[16];
      float mt = -1e30f;
#pragma unroll
      for (int st = 0; st < 4; ++st) {
        const size_t krow = (size_t)(t0 + st * 16 + l15) * HD + g * 8;
        bf16x8 a0 = *reinterpret_cast<const bf16x8*>(khh + krow);
        bf16x8 a1 = *reinterpret_cast<const bf16x8*>(khh + krow + 32);
        f32x4 d = (f32x4){0.f, 0.f, 0.f, 0.f};
        d = __builtin_amdgcn_mfma_f32_16x16x32_bf16(a0, qf[0], d, 0, 0, 0);
        d = __builtin_amdgcn_mfma_f32_16x16x32_bf16(a1, qf[1], d, 0, 0, 0);
#pragma unroll
        for (int r = 0; r < 4; ++r) {
          bool ok = lane_on && (!diag || (t0 + st * 16 + 4 * g + r <= myS));
          float sv = ok ? d[r] * 0.125f : -1e30f;
          p[st * 4 + r] = sv;
          mt = fmaxf(mt, sv);
        }
      }
      mt = fmaxf(mt, __shfl_xor(mt, 16));
      mt = fmaxf(mt, __shfl_xor(mt, 32));
      const float mnew = fmaxf(m, mt);
      const float corr = __expf(m - mnew);
      float ps = 0.f;
#pragma unroll
      for (int i = 0; i < 16; ++i) {
        float pv = (p[i] > -1e29f) ? __expf(p[i] - mnew) : 0.f;
        p[i] = pv;
        ps += pv;
      }
      ps += __shfl_xor(ps, 16);
      ps += __shfl_xor(ps, 32);
      lsum = lsum * corr + ps;
      m = mnew;

      // Rescale accumulator: acc rows are q-rows 4g+r; corr lives at lane 4g+r
#pragma unroll
      for (int r = 0; r < 4; ++r) {
        float cr = __shfl(corr, 4 * g + r);
#pragma unroll
        for (int cb = 0; cb < 4; ++cb) accv[cb][r] *= cr;
      }

      // PV: P fragment (A of 16x16x16) is exactly the S^T output fragment
#pragma unroll
      for (int st = 0; st < 4; ++st) {
        bf16x4 pa;
#pragma unroll
        for (int j = 0; j < 4; ++j) pa[j] = (short)f2bf(p[st * 4 + j]);
#pragma unroll
        for (int cb = 0; cb < 4; ++cb)
          accv[cb] = mfma16(pa, vb[st][cb], accv[cb]);
      }
    }
  }

  const float inv = 1.0f / lsum;
#pragma unroll
  for (int r = 0; r < 4; ++r) {
    float iv = __shfl(inv, 4 * g + r);
    float* op = o + ((size_t)(s0 + 4 * g + r) * NH + h) * HD + l15;
#pragma unroll
    for (int cb = 0; cb < 4; ++cb) op[cb * 16] = accv[cb][r] * iv;
  }
}

// ---------------------------------------------------------------------------
// RMS-norm + sigmoid gate; emits bf16 for the out-proj A-operand.
// ---------------------------------------------------------------------------
__global__ __launch_bounds__(256) void postproc(const float* __restrict__ o,
                                                const float* __restrict__ g,
                                                const float* __restrict__ w,
                                                unsigned short* __restrict__ o2h) {
  int idx = blockIdx.x * 256 + threadIdx.x;
  int lane = threadIdx.x & 63;
  float val = o[idx];
  float ss = val * val;
#pragma unroll
  for (int off = 32; off; off >>= 1) ss += __shfl_xor(ss, off);
  float r = rsqrtf(ss * (1.0f / HD) + 1e-6f);
  float gv = g[idx];
  float sig = 1.0f / (1.0f + expf(-gv));
  o2h[idx] = f2bf(val * r * w[lane] * sig);
}

// ---------------------------------------------------------------------------
extern "C" void kernel_launch(void* const* d_in, const int* in_sizes, int n_in,
                              void* d_out, int out_size, void* d_ws, size_t ws_size,
                              hipStream_t stream) {
  const float* x   = (const float*)d_in[0];
  const float* Wq  = (const float*)d_in[1];
  const float* Wk  = (const float*)d_in[2];
  const float* Wv  = (const float*)d_in[3];
  const float* Wo  = (const float*)d_in[4];
  const float* Wg1 = (const float*)d_in[5];
  const float* Wg2 = (const float*)d_in[6];
  const float* onw = (const float*)d_in[7];
  float* out = (float*)d_out;

  const size_t BIG = (size_t)S_LEN * D_DIM;  // 4M elements
  float* q  = (float*)d_ws;
  float* k  = q + BIG;
  float* v  = k + BIG;
  float* o  = v + BIG;
  float* kg = o + BIG;                        // NCH*NH*HD
  int* amask = (int*)(kg + NCH * NH * HD);    // NH*S
  unsigned short* xh  = (unsigned short*)(amask + NH * S_LEN);
  unsigned short* xl  = xh + BIG;
  unsigned short* whT = xl + BIG;
  unsigned short* wlT = whT + BIG;
  unsigned short* kh  = wlT + BIG;
  unsigned short* vT  = kh + BIG;
  unsigned short* o2h = vT + BIG;

  const dim3 gT(32, 32);
  // Split x into hi/lo bf16
  repack_x_hl<<<(int)(BIG / 4 / 256), 256, 0, stream>>>(x, xh, xl);

  // Q = x@Wq (3-pass hi/lo)
  repack_T<<<gT, 256, 0, stream>>>(Wq, whT, wlT, D_DIM, D_DIM, 1);
  {
    G3 g3{{xh, xh, xl}, {whT, wlT, whT}, 3};
    gemm_bt<<<256, 256, 0, stream>>>(g3, q, S_LEN, D_DIM, D_DIM);
  }
  // K = x@Wk (3-pass hi/lo)
  repack_T<<<gT, 256, 0, stream>>>(Wk, whT, wlT, D_DIM, D_DIM, 1);
  {
    G3 g3{{xh, xh, xl}, {whT, wlT, whT}, 3};
    gemm_bt<<<256, 256, 0, stream>>>(g3, k, S_LEN, D_DIM, D_DIM);
  }
  // V = x@Wv (1-pass bf16)
  repack_T<<<gT, 256, 0, stream>>>(Wv, whT, nullptr, D_DIM, D_DIM, 0);
  {
    G3 g3{{xh, xh, xh}, {whT, whT, whT}, 1};
    gemm_bt<<<256, 256, 0, stream>>>(g3, v, S_LEN, D_DIM, D_DIM);
  }
  // RoPE
  rope_qk<<<S_LEN * NH * (HD / 2) / 256, 256, 0, stream>>>(q, k);
  // Chunk means + gating (fp32)
  chunk_mean<<<(NCH * NH * HD + 255) / 256, 256, 0, stream>>>(k, kg);
  gate_topk<<<dim3(S_LEN / 4, NH), 256, 0, stream>>>(q, kg, amask);
  // Repack for MFMA attention
  repack_k<<<(int)(BIG / 4 / 256), 256, 0, stream>>>(k, kh);
  repack_vT<<<dim3(S_LEN / 64, NH), 256, 0, stream>>>(v, vT);
  // W' = Wg1 @ Wg2 (fp32, K=64) into o; then repack to bf16 T
  sgemm_f32<<<dim3(16, 16), 256, 0, stream>>>(Wg1, Wg2, o, D_DIM, D_DIM, HD);
  repack_T<<<gT, 256, 0, stream>>>(o, whT, nullptr, D_DIM, D_DIM, 0);
  // Attention (overwrites o)
  attn_mfma<<<dim3(S_LEN / 16, NH), 64, 0, stream>>>(q, kh, vT, amask, o);
  // g = x @ W' (1-pass bf16) into k buffer
  {
    G3 g3{{xh, xh, xh}, {whT, whT, whT}, 1};
    gemm_bt<<<256, 256, 0, stream>>>(g3, k, S_LEN, D_DIM, D_DIM);
  }
  // RMS-norm + sigmoid gate -> bf16
  postproc<<<(int)(BIG / 256), 256, 0, stream>>>(o, k, onw, o2h);
  // out = o2 @ Wo (1-pass bf16)
  repack_T<<<gT, 256, 0, stream>>>(Wo, whT, nullptr, D_DIM, D_DIM, 0);
  {
    G3 g3{{o2h, o2h, o2h}, {whT, whT, whT}, 1};
    gemm_bt<<<256, 256, 0, stream>>>(g3, out, S_LEN, D_DIM, D_DIM);
  }
}

// Round 6
// 682.789 us; speedup vs baseline: 1.1553x; 1.1379x over previous
//
#include <hip/hip_runtime.h>
#include <hip/hip_bf16.h>
#include <math.h>

#define S_LEN 2048
#define D_DIM 2048
#define NH 32
#define HD 64
#define CS 256
#define NCH 8

typedef __attribute__((ext_vector_type(8))) short bf16x8;
typedef __attribute__((ext_vector_type(4))) short bf16x4;
typedef __attribute__((ext_vector_type(4))) float f32x4;

__device__ __forceinline__ unsigned short f2bf(float f) {
  unsigned int u = __builtin_bit_cast(unsigned int, f);
  unsigned int r = (u + 0x7fffu + ((u >> 16) & 1u)) >> 16;
  return (unsigned short)r;
}
__device__ __forceinline__ float bf2f(unsigned short b) {
  unsigned int u = ((unsigned int)b) << 16;
  return __builtin_bit_cast(float, u);
}

__device__ __forceinline__ f32x4 mfma16(bf16x4 a, bf16x4 b, f32x4 c) {
#if __has_builtin(__builtin_amdgcn_mfma_f32_16x16x16_bf16)
  return __builtin_amdgcn_mfma_f32_16x16x16_bf16(a, b, c, 0, 0, 0);
#elif __has_builtin(__builtin_amdgcn_mfma_f32_16x16x16bf16_1k)
  return __builtin_amdgcn_mfma_f32_16x16x16bf16_1k(a, b, c, 0, 0, 0);
#else
  asm("v_mfma_f32_16x16x16_bf16 %0, %1, %2, %0" : "+v"(c) : "v"(a), "v"(b));
  return c;
#endif
}

__device__ __forceinline__ void gload16(const void* gp, void* lp) {
  __builtin_amdgcn_global_load_lds(
      (const __attribute__((address_space(1))) unsigned int*)gp,
      (__attribute__((address_space(3))) unsigned int*)lp, 16, 0, 0);
}

// ---------------------------------------------------------------------------
// bf16 MFMA GEMM: C(MxN fp32) = sum_p A_p(MxK bf16) @ B_p^T(NxK bf16).
// ---------------------------------------------------------------------------
struct G3 {
  const unsigned short* A[3];
  const unsigned short* B[3];
  int np;
};

__global__ __launch_bounds__(256) void gemm_bt(G3 g, float* __restrict__ C,
                                               int M, int N, int K) {
  __shared__ __align__(16) unsigned short Als[128 * 64];
  __shared__ __align__(16) unsigned short Bls[128 * 64];
  const int tid = threadIdx.x;
  const int wid = tid >> 6, lane = tid & 63;
  const int l15 = lane & 15, l4 = lane >> 4;
  const int wr = wid >> 1, wc = wid & 1;
  const int nbx = N >> 7;
  int bid = blockIdx.x;
  const int nwg = gridDim.x;
  if ((nwg & 7) == 0) {  // bijective XCD swizzle
    int q = nwg >> 3;
    bid = (bid & 7) * q + (bid >> 3);
  }
  const int row0 = (bid / nbx) << 7;
  const int col0 = (bid % nbx) << 7;

  f32x4 acc[4][4];
#pragma unroll
  for (int m = 0; m < 4; ++m)
#pragma unroll
    for (int n = 0; n < 4; ++n) acc[m][n] = (f32x4){0.f, 0.f, 0.f, 0.f};

  for (int p = 0; p < g.np; ++p) {
    const unsigned short* Ap = g.A[p];
    const unsigned short* Bp = g.B[p];
    for (int kt = 0; kt < K; kt += 64) {
      __syncthreads();
#pragma unroll
      for (int i = 0; i < 4; ++i) {
        const int Lb = i * 4096 + wid * 1024;
        const int L = Lb + lane * 16;
        const int row = L >> 7;
        const int s = (L >> 4) & 7;
        const int cofs = (s ^ (row & 7)) << 3;
        gload16(Ap + (size_t)(row0 + row) * K + kt + cofs, (char*)Als + Lb);
        gload16(Bp + (size_t)(col0 + row) * K + kt + cofs, (char*)Bls + Lb);
      }
      asm volatile("s_waitcnt vmcnt(0)" ::: "memory");
      __syncthreads();
#pragma unroll
      for (int ks = 0; ks < 2; ++ks) {
        bf16x8 af[4], bfr[4];
#pragma unroll
        for (int m = 0; m < 4; ++m) {
          int row = wr * 64 + m * 16 + l15;
          int s = (ks * 4 + l4) ^ (row & 7);
          af[m] = *reinterpret_cast<const bf16x8*>(&Als[row * 64 + s * 8]);
        }
#pragma unroll
        for (int n = 0; n < 4; ++n) {
          int col = wc * 64 + n * 16 + l15;
          int s = (ks * 4 + l4) ^ (col & 7);
          bfr[n] = *reinterpret_cast<const bf16x8*>(&Bls[col * 64 + s * 8]);
        }
#pragma unroll
        for (int m = 0; m < 4; ++m)
#pragma unroll
          for (int n = 0; n < 4; ++n)
            acc[m][n] = __builtin_amdgcn_mfma_f32_16x16x32_bf16(af[m], bfr[n], acc[m][n], 0, 0, 0);
      }
    }
  }

#pragma unroll
  for (int m = 0; m < 4; ++m)
#pragma unroll
    for (int n = 0; n < 4; ++n)
#pragma unroll
      for (int r = 0; r < 4; ++r)
        C[(size_t)(row0 + wr * 64 + m * 16 + l4 * 4 + r) * N + col0 + wc * 64 + n * 16 + l15] =
            acc[m][n][r];
}

// ---------------------------------------------------------------------------
// fp32 SGEMM (kept only for W' = Wg1 @ Wg2, K=64).
// ---------------------------------------------------------------------------
__global__ __launch_bounds__(256) void sgemm_f32(const float* __restrict__ A,
                                                 const float* __restrict__ B,
                                                 float* __restrict__ C,
                                                 int M, int N, int K) {
  __shared__ float As[8][128];
  __shared__ float Bs[8][128];
  const int tid = threadIdx.x;
  const int row0 = blockIdx.y * 128;
  const int col0 = blockIdx.x * 128;
  const int tm = (tid / 16) * 8;
  const int tn = (tid % 16) * 8;
  const int arow = tid >> 1;
  const int acol = (tid & 1) * 4;
  const int brow = tid >> 5;
  const int bcol = (tid & 31) * 4;

  float acc[8][8];
#pragma unroll
  for (int i = 0; i < 8; ++i)
#pragma unroll
    for (int j = 0; j < 8; ++j) acc[i][j] = 0.f;

  for (int k0 = 0; k0 < K; k0 += 8) {
    float4 av = make_float4(0.f, 0.f, 0.f, 0.f);
    if (row0 + arow < M) {
      int kb = k0 + acol;
      av = *reinterpret_cast<const float4*>(&A[(size_t)(row0 + arow) * K + kb]);
    }
    As[acol + 0][arow] = av.x;
    As[acol + 1][arow] = av.y;
    As[acol + 2][arow] = av.z;
    As[acol + 3][arow] = av.w;
    float4 bv = make_float4(0.f, 0.f, 0.f, 0.f);
    if (k0 + brow < K) {
      bv = *reinterpret_cast<const float4*>(&B[(size_t)(k0 + brow) * N + col0 + bcol]);
    }
    *reinterpret_cast<float4*>(&Bs[brow][bcol]) = bv;
    __syncthreads();
#pragma unroll
    for (int kk = 0; kk < 8; ++kk) {
      float a[8], b[8];
      *reinterpret_cast<float4*>(&a[0]) = *reinterpret_cast<const float4*>(&As[kk][tm]);
      *reinterpret_cast<float4*>(&a[4]) = *reinterpret_cast<const float4*>(&As[kk][tm + 4]);
      *reinterpret_cast<float4*>(&b[0]) = *reinterpret_cast<const float4*>(&Bs[kk][tn]);
      *reinterpret_cast<float4*>(&b[4]) = *reinterpret_cast<const float4*>(&Bs[kk][tn + 4]);
#pragma unroll
      for (int i = 0; i < 8; ++i)
#pragma unroll
        for (int j = 0; j < 8; ++j) acc[i][j] = fmaf(a[i], b[j], acc[i][j]);
    }
    __syncthreads();
  }
#pragma unroll
  for (int i = 0; i < 8; ++i) {
    int r = row0 + tm + i;
    if (r < M) {
#pragma unroll
      for (int j = 0; j < 8; ++j) {
        int c = col0 + tn + j;
        if (c < N) C[(size_t)r * N + c] = acc[i][j];
      }
    }
  }
}

// ---------------------------------------------------------------------------
// x fp32 -> xh, xl bf16 (hi/lo split), same layout.
// ---------------------------------------------------------------------------
__global__ __launch_bounds__(256) void repack_x_hl(const float* __restrict__ x,
                                                   unsigned short* __restrict__ xh,
                                                   unsigned short* __restrict__ xl) {
  int i = (blockIdx.x * 256 + threadIdx.x) * 4;
  float4 v = *reinterpret_cast<const float4*>(&x[i]);
  float f[4] = {v.x, v.y, v.z, v.w};
  unsigned short h[4], l[4];
#pragma unroll
  for (int j = 0; j < 4; ++j) {
    h[j] = f2bf(f[j]);
    l[j] = f2bf(f[j] - bf2f(h[j]));
  }
  *reinterpret_cast<ushort4*>(&xh[i]) = make_ushort4(h[0], h[1], h[2], h[3]);
  *reinterpret_cast<ushort4*>(&xl[i]) = make_ushort4(l[0], l[1], l[2], l[3]);
}

// ---------------------------------------------------------------------------
// W (rows x cols, fp32) -> W^T bf16 hi (and optional lo), (cols x rows).
// ---------------------------------------------------------------------------
__global__ __launch_bounds__(256) void repack_T(const float* __restrict__ W,
                                                unsigned short* __restrict__ hiT,
                                                unsigned short* __restrict__ loT,
                                                int rows, int cols, int has_lo) {
  __shared__ float t[64][65];
  const int k0 = blockIdx.y * 64, n0 = blockIdx.x * 64;
  const int tid = threadIdx.x;
  const int c = tid & 63, rr = tid >> 6;
#pragma unroll
  for (int r = 0; r < 16; ++r) {
    int kr = r * 4 + rr;
    t[kr][c] = W[(size_t)(k0 + kr) * cols + n0 + c];
  }
  __syncthreads();
#pragma unroll
  for (int r = 0; r < 16; ++r) {
    int n = r * 4 + rr;
    float f = t[c][n];
    unsigned short hb = f2bf(f);
    hiT[(size_t)(n0 + n) * rows + k0 + c] = hb;
    if (has_lo) loT[(size_t)(n0 + n) * rows + k0 + c] = f2bf(f - bf2f(hb));
  }
}

// ---------------------------------------------------------------------------
// RoPE applied in-place to q and k.
// ---------------------------------------------------------------------------
__global__ __launch_bounds__(256) void rope_qk(float* __restrict__ q, float* __restrict__ kk) {
  int idx = blockIdx.x * 256 + threadIdx.x;
  if (idx >= S_LEN * NH * (HD / 2)) return;
  int d = idx & 31;
  int sh = idx >> 5;
  int s = sh >> 5;
  float inv = 1.0f / powf(10000.0f, (float)d * (1.0f / 32.0f));
  float fr = (float)s * inv;
  float c = cosf(fr), sn = sinf(fr);
  size_t base = (size_t)sh * HD + d;
  float q1 = q[base], q2 = q[base + 32];
  q[base] = q1 * c - q2 * sn;
  q[base + 32] = q2 * c + q1 * sn;
  float k1 = kk[base], k2 = kk[base + 32];
  kk[base] = k1 * c - k2 * sn;
  kk[base + 32] = k2 * c + k1 * sn;
}

// ---------------------------------------------------------------------------
// Chunk means of k.
// ---------------------------------------------------------------------------
__global__ __launch_bounds__(256) void chunk_mean(const float* __restrict__ k,
                                                  float* __restrict__ kg) {
  int idx = blockIdx.x * 256 + threadIdx.x;
  if (idx >= NCH * NH * HD) return;
  int c = idx / (NH * HD);
  int hd = idx % (NH * HD);
  float sum = 0.f;
  for (int t = 0; t < CS; ++t) sum += k[(size_t)(c * CS + t) * (NH * HD) + hd];
  kg[idx] = sum * (1.0f / CS);
}

// ---------------------------------------------------------------------------
// Gate + top-3-past chunk selection (fp32 — selection must stay exact).
// ---------------------------------------------------------------------------
__global__ __launch_bounds__(256) void gate_topk(const float* __restrict__ q,
                                                 const float* __restrict__ kg,
                                                 int* __restrict__ amask) {
  int wid = threadIdx.x >> 6;
  int lane = threadIdx.x & 63;
  int s = blockIdx.x * 4 + wid;
  int h = blockIdx.y;
  int myc = s >> 8;
  float qd = q[((size_t)s * NH + h) * HD + lane];
  float g[NCH];
#pragma unroll
  for (int c = 0; c < NCH; ++c) {
    float p = qd * kg[((size_t)c * NH + h) * HD + lane];
#pragma unroll
    for (int off = 32; off; off >>= 1) p += __shfl_xor(p, off);
    g[c] = p;
  }
  int chosen = 0;
#pragma unroll
  for (int pick = 0; pick < 3; ++pick) {
    float best = -INFINITY;
    int bi = -1;
#pragma unroll
    for (int c = 0; c < NCH; ++c) {
      if (c < myc && !((chosen >> c) & 1) && g[c] > best) {
        best = g[c];
        bi = c;
      }
    }
    if (bi >= 0) chosen |= (1 << bi);
  }
  int mask = chosen | (1 << myc);
  if (lane == 0) amask[h * S_LEN + s] = mask;
}

// ---------------------------------------------------------------------------
// Repack k fp32 [s][h][d] -> kh bf16 [h][s][d]
// ---------------------------------------------------------------------------
__global__ __launch_bounds__(256) void repack_k(const float* __restrict__ k,
                                                unsigned short* __restrict__ kh) {
  int t = blockIdx.x * 256 + threadIdx.x;
  int d4 = (t & 15) * 4;
  int s = (t >> 4) & (S_LEN - 1);
  int h = t >> 15;
  float4 v = *reinterpret_cast<const float4*>(&k[(((size_t)s * NH + h) * HD + d4)]);
  size_t oi = ((size_t)h * S_LEN + s) * HD + d4;
  *reinterpret_cast<ushort4*>(&kh[oi]) =
      make_ushort4(f2bf(v.x), f2bf(v.y), f2bf(v.z), f2bf(v.w));
}

// ---------------------------------------------------------------------------
// Repack v fp32 [s][h][d] -> vT bf16 [h][d][s]  (LDS transpose)
// ---------------------------------------------------------------------------
__global__ __launch_bounds__(256) void repack_vT(const float* __restrict__ v,
                                                 unsigned short* __restrict__ vT) {
  __shared__ float tile[64][65];
  const int h = blockIdx.y;
  const int sb = blockIdx.x * 64;
  const int tid = threadIdx.x;
#pragma unroll
  for (int r = 0; r < 16; ++r) {
    int row = r * 4 + (tid >> 6);
    int d = tid & 63;
    tile[row][d] = v[((size_t)(sb + row) * NH + h) * HD + d];
  }
  __syncthreads();
#pragma unroll
  for (int r = 0; r < 16; ++r) {
    int d = r * 4 + (tid >> 6);
    int si = tid & 63;
    vT[((size_t)h * HD + d) * S_LEN + sb + si] = f2bf(tile[si][d]);
  }
}

// ---------------------------------------------------------------------------
// MFMA flash attention, split-K across 4 waves per workgroup.
// Workgroup = 256 threads = 4 waves handles 16 q-rows of one head.
// Tiles of the union chunk list are dealt round-robin to waves
// (tile_index % 4 == wid); partial (m, l, acc) merged through LDS.
// ---------------------------------------------------------------------------
__global__ __launch_bounds__(256) void attn_mfma(const float* __restrict__ q,
                                                 const unsigned short* __restrict__ kh,
                                                 const unsigned short* __restrict__ vT,
                                                 const int* __restrict__ amask,
                                                 float* __restrict__ o) {
  const int h = blockIdx.y;
  const int tid = threadIdx.x;
  const int wid = tid >> 6;
  const int lane = tid & 63;
  const int l15 = lane & 15, g = lane >> 4;
  const int s0 = blockIdx.x * 16;
  const int myS = s0 + l15;
  const int myc = s0 >> 8;

  __shared__ float lm[4][16];
  __shared__ float ll[4][16];
  __shared__ float lacc[4][16][64];  // [wave][reg(cb*4+r)][lane] — lane-major, conflict-free

  // Q B-frag (16x16x32): lane holds Q[row=l15][hd=hf*32+g*8+j]
  const float* qrow = q + ((size_t)myS * NH + h) * HD;
  bf16x8 qf[2];
#pragma unroll
  for (int hf = 0; hf < 2; ++hf)
#pragma unroll
    for (int j = 0; j < 8; ++j) qf[hf][j] = (short)f2bf(qrow[hf * 32 + g * 8 + j]);

  int mymask = amask[h * S_LEN + myS];
  int wmask = mymask;
  wmask |= __shfl_xor(wmask, 1);
  wmask |= __shfl_xor(wmask, 2);
  wmask |= __shfl_xor(wmask, 4);
  wmask |= __shfl_xor(wmask, 8);

  float m = -1e30f, lsum = 0.f;
  f32x4 accv[4];
#pragma unroll
  for (int i = 0; i < 4; ++i) accv[i] = (f32x4){0.f, 0.f, 0.f, 0.f};

  const int ktm = (s0 & (CS - 1)) >> 6;
  const unsigned short* khh = kh + (size_t)h * S_LEN * HD;
  const unsigned short* vth = vT + (size_t)h * HD * S_LEN;

  int tcnt = 0;
  for (int c = 0; c <= myc; ++c) {
    if (!((wmask >> c) & 1)) continue;
    const bool lane_on = (mymask >> c) & 1;
    const int nkt = (c == myc) ? (ktm + 1) : 4;
    for (int kt = 0; kt < nkt; ++kt, ++tcnt) {
      if ((tcnt & 3) != wid) continue;
      const int t0 = c * CS + kt * 64;
      const bool diag = (c == myc) && (kt == ktm);

      // Prefetch V B-frags (16x16x16)
      bf16x4 vb[4][4];
#pragma unroll
      for (int st = 0; st < 4; ++st)
#pragma unroll
        for (int cb = 0; cb < 4; ++cb)
          vb[st][cb] = *reinterpret_cast<const bf16x4*>(
              vth + (size_t)(cb * 16 + l15) * S_LEN + t0 + st * 16 + 4 * g);

      // S^T tile: 4 key-subtiles x 2 hd-halves
      float p[16];
      float mt = -1e30f;
#pragma unroll
      for (int st = 0; st < 4; ++st) {
        const size_t krow = (size_t)(t0 + st * 16 + l15) * HD + g * 8;
        bf16x8 a0 = *reinterpret_cast<const bf16x8*>(khh + krow);
        bf16x8 a1 = *reinterpret_cast<const bf16x8*>(khh + krow + 32);
        f32x4 d = (f32x4){0.f, 0.f, 0.f, 0.f};
        d = __builtin_amdgcn_mfma_f32_16x16x32_bf16(a0, qf[0], d, 0, 0, 0);
        d = __builtin_amdgcn_mfma_f32_16x16x32_bf16(a1, qf[1], d, 0, 0, 0);
#pragma unroll
        for (int r = 0; r < 4; ++r) {
          bool ok = lane_on && (!diag || (t0 + st * 16 + 4 * g + r <= myS));
          float sv = ok ? d[r] * 0.125f : -1e30f;
          p[st * 4 + r] = sv;
          mt = fmaxf(mt, sv);
        }
      }
      mt = fmaxf(mt, __shfl_xor(mt, 16));
      mt = fmaxf(mt, __shfl_xor(mt, 32));
      const float mnew = fmaxf(m, mt);
      const float corr = __expf(m - mnew);
      float ps = 0.f;
#pragma unroll
      for (int i = 0; i < 16; ++i) {
        float pv = (p[i] > -1e29f) ? __expf(p[i] - mnew) : 0.f;
        p[i] = pv;
        ps += pv;
      }
      ps += __shfl_xor(ps, 16);
      ps += __shfl_xor(ps, 32);
      lsum = lsum * corr + ps;
      m = mnew;

      // Rescale accumulator (acc rows are q-rows 4g+r; corr lives at lane 4g+r)
#pragma unroll
      for (int r = 0; r < 4; ++r) {
        float cr = __shfl(corr, 4 * g + r);
#pragma unroll
        for (int cb = 0; cb < 4; ++cb) accv[cb][r] *= cr;
      }

      // PV: P fragment (A of 16x16x16) is exactly the S^T output fragment
#pragma unroll
      for (int st = 0; st < 4; ++st) {
        bf16x4 pa;
#pragma unroll
        for (int j = 0; j < 4; ++j) pa[j] = (short)f2bf(p[st * 4 + j]);
#pragma unroll
        for (int cb = 0; cb < 4; ++cb)
          accv[cb] = mfma16(pa, vb[st][cb], accv[cb]);
      }
    }
  }

  // ---- store partials to LDS ----
#pragma unroll
  for (int cb = 0; cb < 4; ++cb)
#pragma unroll
    for (int r = 0; r < 4; ++r) lacc[wid][cb * 4 + r][lane] = accv[cb][r];
  if (lane < 16) {
    lm[wid][lane] = m;
    ll[wid][lane] = lsum;
  }
  __syncthreads();

  // ---- merge: wave `wid` produces dim-block cb = wid ----
  float outv[4];
#pragma unroll
  for (int r = 0; r < 4; ++r) {
    const int row = 4 * g + r;
    float m0 = lm[0][row], m1 = lm[1][row], m2 = lm[2][row], m3 = lm[3][row];
    float mt = fmaxf(fmaxf(m0, m1), fmaxf(m2, m3));
    float e0 = __expf(m0 - mt), e1 = __expf(m1 - mt);
    float e2 = __expf(m2 - mt), e3 = __expf(m3 - mt);
    float ltot = ll[0][row] * e0 + ll[1][row] * e1 + ll[2][row] * e2 + ll[3][row] * e3;
    float a = lacc[0][wid * 4 + r][lane] * e0 + lacc[1][wid * 4 + r][lane] * e1 +
              lacc[2][wid * 4 + r][lane] * e2 + lacc[3][wid * 4 + r][lane] * e3;
    outv[r] = a / ltot;
  }
#pragma unroll
  for (int r = 0; r < 4; ++r)
    o[((size_t)(s0 + 4 * g + r) * NH + h) * HD + wid * 16 + l15] = outv[r];
}

// ---------------------------------------------------------------------------
// RMS-norm + sigmoid gate; emits bf16 for the out-proj A-operand.
// ---------------------------------------------------------------------------
__global__ __launch_bounds__(256) void postproc(const float* __restrict__ o,
                                                const float* __restrict__ g,
                                                const float* __restrict__ w,
                                                unsigned short* __restrict__ o2h) {
  int idx = blockIdx.x * 256 + threadIdx.x;
  int lane = threadIdx.x & 63;
  float val = o[idx];
  float ss = val * val;
#pragma unroll
  for (int off = 32; off; off >>= 1) ss += __shfl_xor(ss, off);
  float r = rsqrtf(ss * (1.0f / HD) + 1e-6f);
  float gv = g[idx];
  float sig = 1.0f / (1.0f + expf(-gv));
  o2h[idx] = f2bf(val * r * w[lane] * sig);
}

// ---------------------------------------------------------------------------
extern "C" void kernel_launch(void* const* d_in, const int* in_sizes, int n_in,
                              void* d_out, int out_size, void* d_ws, size_t ws_size,
                              hipStream_t stream) {
  const float* x   = (const float*)d_in[0];
  const float* Wq  = (const float*)d_in[1];
  const float* Wk  = (const float*)d_in[2];
  const float* Wv  = (const float*)d_in[3];
  const float* Wo  = (const float*)d_in[4];
  const float* Wg1 = (const float*)d_in[5];
  const float* Wg2 = (const float*)d_in[6];
  const float* onw = (const float*)d_in[7];
  float* out = (float*)d_out;

  const size_t BIG = (size_t)S_LEN * D_DIM;  // 4M elements
  float* q  = (float*)d_ws;
  float* k  = q + BIG;
  float* v  = k + BIG;
  float* o  = v + BIG;
  float* kg = o + BIG;                        // NCH*NH*HD
  int* amask = (int*)(kg + NCH * NH * HD);    // NH*S
  unsigned short* xh  = (unsigned short*)(amask + NH * S_LEN);
  unsigned short* xl  = xh + BIG;
  unsigned short* whT = xl + BIG;
  unsigned short* wlT = whT + BIG;
  unsigned short* kh  = wlT + BIG;
  unsigned short* vT  = kh + BIG;
  unsigned short* o2h = vT + BIG;

  const dim3 gT(32, 32);
  // Split x into hi/lo bf16
  repack_x_hl<<<(int)(BIG / 4 / 256), 256, 0, stream>>>(x, xh, xl);

  // Q = x@Wq (3-pass hi/lo)
  repack_T<<<gT, 256, 0, stream>>>(Wq, whT, wlT, D_DIM, D_DIM, 1);
  {
    G3 g3{{xh, xh, xl}, {whT, wlT, whT}, 3};
    gemm_bt<<<256, 256, 0, stream>>>(g3, q, S_LEN, D_DIM, D_DIM);
  }
  // K = x@Wk (3-pass hi/lo)
  repack_T<<<gT, 256, 0, stream>>>(Wk, whT, wlT, D_DIM, D_DIM, 1);
  {
    G3 g3{{xh, xh, xl}, {whT, wlT, whT}, 3};
    gemm_bt<<<256, 256, 0, stream>>>(g3, k, S_LEN, D_DIM, D_DIM);
  }
  // V = x@Wv (1-pass bf16)
  repack_T<<<gT, 256, 0, stream>>>(Wv, whT, nullptr, D_DIM, D_DIM, 0);
  {
    G3 g3{{xh, xh, xh}, {whT, whT, whT}, 1};
    gemm_bt<<<256, 256, 0, stream>>>(g3, v, S_LEN, D_DIM, D_DIM);
  }
  // RoPE
  rope_qk<<<S_LEN * NH * (HD / 2) / 256, 256, 0, stream>>>(q, k);
  // Chunk means + gating (fp32)
  chunk_mean<<<(NCH * NH * HD + 255) / 256, 256, 0, stream>>>(k, kg);
  gate_topk<<<dim3(S_LEN / 4, NH), 256, 0, stream>>>(q, kg, amask);
  // Repack for MFMA attention
  repack_k<<<(int)(BIG / 4 / 256), 256, 0, stream>>>(k, kh);
  repack_vT<<<dim3(S_LEN / 64, NH), 256, 0, stream>>>(v, vT);
  // W' = Wg1 @ Wg2 (fp32, K=64) into o; then repack to bf16 T
  sgemm_f32<<<dim3(16, 16), 256, 0, stream>>>(Wg1, Wg2, o, D_DIM, D_DIM, HD);
  repack_T<<<gT, 256, 0, stream>>>(o, whT, nullptr, D_DIM, D_DIM, 0);
  // Attention (overwrites o): 4-wave split-K per 16 q-rows
  attn_mfma<<<dim3(S_LEN / 16, NH), 256, 0, stream>>>(q, kh, vT, amask, o);
  // g = x @ W' (1-pass bf16) into k buffer
  {
    G3 g3{{xh, xh, xh}, {whT, whT, whT}, 1};
    gemm_bt<<<256, 256, 0, stream>>>(g3, k, S_LEN, D_DIM, D_DIM);
  }
  // RMS-norm + sigmoid gate -> bf16
  postproc<<<(int)(BIG / 256), 256, 0, stream>>>(o, k, onw, o2h);
  // out = o2 @ Wo (1-pass bf16)
  repack_T<<<gT, 256, 0, stream>>>(Wo, whT, nullptr, D_DIM, D_DIM, 0);
  {
    G3 g3{{o2h, o2h, o2h}, {whT, whT, whT}, 1};
    gemm_bt<<<256, 256, 0, stream>>>(g3, out, S_LEN, D_DIM, D_DIM);
  }
}

// Round 7
// 595.998 us; speedup vs baseline: 1.3235x; 1.1456x over previous
//
#include <hip/hip_runtime.h>
#include <hip/hip_bf16.h>
#include <math.h>

#define S_LEN 2048
#define D_DIM 2048
#define NH 32
#define HD 64
#define CS 256
#define NCH 8

typedef __attribute__((ext_vector_type(8))) short bf16x8;
typedef __attribute__((ext_vector_type(4))) short bf16x4;
typedef __attribute__((ext_vector_type(4))) float f32x4;

__device__ __forceinline__ unsigned short f2bf(float f) {
  unsigned int u = __builtin_bit_cast(unsigned int, f);
  unsigned int r = (u + 0x7fffu + ((u >> 16) & 1u)) >> 16;
  return (unsigned short)r;
}
__device__ __forceinline__ float bf2f(unsigned short b) {
  unsigned int u = ((unsigned int)b) << 16;
  return __builtin_bit_cast(float, u);
}

__device__ __forceinline__ f32x4 mfma16(bf16x4 a, bf16x4 b, f32x4 c) {
#if __has_builtin(__builtin_amdgcn_mfma_f32_16x16x16_bf16)
  return __builtin_amdgcn_mfma_f32_16x16x16_bf16(a, b, c, 0, 0, 0);
#elif __has_builtin(__builtin_amdgcn_mfma_f32_16x16x16bf16_1k)
  return __builtin_amdgcn_mfma_f32_16x16x16bf16_1k(a, b, c, 0, 0, 0);
#else
  asm("v_mfma_f32_16x16x16_bf16 %0, %1, %2, %0" : "+v"(c) : "v"(a), "v"(b));
  return c;
#endif
}

__device__ __forceinline__ void gload16(const void* gp, void* lp) {
  __builtin_amdgcn_global_load_lds(
      (const __attribute__((address_space(1))) unsigned int*)gp,
      (__attribute__((address_space(3))) unsigned int*)lp, 16, 0, 0);
}

// ---------------------------------------------------------------------------
// bf16 MFMA GEMM: C(MxN fp32) = sum_p A_p(MxK bf16) @ B_p^T(NxK bf16).
// 64x128 tile, BK=64, 4 waves (each 32x64). 512 blocks at 2048x2048 ->
// 2 blocks/CU (128^2 gave only 1/CU).
// ---------------------------------------------------------------------------
struct G3 {
  const unsigned short* A[3];
  const unsigned short* B[3];
  int np;
};

__global__ __launch_bounds__(256) void gemm_bt(G3 g, float* __restrict__ C,
                                               int M, int N, int K) {
  __shared__ __align__(16) unsigned short Als[64 * 64];
  __shared__ __align__(16) unsigned short Bls[128 * 64];
  const int tid = threadIdx.x;
  const int wid = tid >> 6, lane = tid & 63;
  const int l15 = lane & 15, l4 = lane >> 4;
  const int wr = wid >> 1, wc = wid & 1;
  const int nbx = N >> 7;
  int bid = blockIdx.x;
  const int nwg = gridDim.x;
  if ((nwg & 7) == 0) {  // bijective XCD swizzle
    int q = nwg >> 3;
    bid = (bid & 7) * q + (bid >> 3);
  }
  const int row0 = (bid / nbx) << 6;
  const int col0 = (bid % nbx) << 7;

  f32x4 acc[2][4];
#pragma unroll
  for (int m = 0; m < 2; ++m)
#pragma unroll
    for (int n = 0; n < 4; ++n) acc[m][n] = (f32x4){0.f, 0.f, 0.f, 0.f};

  for (int p = 0; p < g.np; ++p) {
    const unsigned short* Ap = g.A[p];
    const unsigned short* Bp = g.B[p];
    for (int kt = 0; kt < K; kt += 64) {
      __syncthreads();
      // A: 64x64 = 8KB -> 2 rounds; B: 128x64 = 16KB -> 4 rounds
#pragma unroll
      for (int i = 0; i < 2; ++i) {
        const int Lb = i * 4096 + wid * 1024;
        const int L = Lb + lane * 16;
        const int row = L >> 7;
        const int s = (L >> 4) & 7;
        const int cofs = (s ^ (row & 7)) << 3;
        gload16(Ap + (size_t)(row0 + row) * K + kt + cofs, (char*)Als + Lb);
      }
#pragma unroll
      for (int i = 0; i < 4; ++i) {
        const int Lb = i * 4096 + wid * 1024;
        const int L = Lb + lane * 16;
        const int row = L >> 7;
        const int s = (L >> 4) & 7;
        const int cofs = (s ^ (row & 7)) << 3;
        gload16(Bp + (size_t)(col0 + row) * K + kt + cofs, (char*)Bls + Lb);
      }
      asm volatile("s_waitcnt vmcnt(0)" ::: "memory");
      __syncthreads();
#pragma unroll
      for (int ks = 0; ks < 2; ++ks) {
        bf16x8 af[2], bfr[4];
#pragma unroll
        for (int m = 0; m < 2; ++m) {
          int row = wr * 32 + m * 16 + l15;
          int s = (ks * 4 + l4) ^ (row & 7);
          af[m] = *reinterpret_cast<const bf16x8*>(&Als[row * 64 + s * 8]);
        }
#pragma unroll
        for (int n = 0; n < 4; ++n) {
          int col = wc * 64 + n * 16 + l15;
          int s = (ks * 4 + l4) ^ (col & 7);
          bfr[n] = *reinterpret_cast<const bf16x8*>(&Bls[col * 64 + s * 8]);
        }
#pragma unroll
        for (int m = 0; m < 2; ++m)
#pragma unroll
          for (int n = 0; n < 4; ++n)
            acc[m][n] = __builtin_amdgcn_mfma_f32_16x16x32_bf16(af[m], bfr[n], acc[m][n], 0, 0, 0);
      }
    }
  }

#pragma unroll
  for (int m = 0; m < 2; ++m)
#pragma unroll
    for (int n = 0; n < 4; ++n)
#pragma unroll
      for (int r = 0; r < 4; ++r)
        C[(size_t)(row0 + wr * 32 + m * 16 + l4 * 4 + r) * N + col0 + wc * 64 + n * 16 + l15] =
            acc[m][n][r];
}

// ---------------------------------------------------------------------------
// fp32 SGEMM (kept only for W' = Wg1 @ Wg2, K=64).
// ---------------------------------------------------------------------------
__global__ __launch_bounds__(256) void sgemm_f32(const float* __restrict__ A,
                                                 const float* __restrict__ B,
                                                 float* __restrict__ C,
                                                 int M, int N, int K) {
  __shared__ float As[8][128];
  __shared__ float Bs[8][128];
  const int tid = threadIdx.x;
  const int row0 = blockIdx.y * 128;
  const int col0 = blockIdx.x * 128;
  const int tm = (tid / 16) * 8;
  const int tn = (tid % 16) * 8;
  const int arow = tid >> 1;
  const int acol = (tid & 1) * 4;
  const int brow = tid >> 5;
  const int bcol = (tid & 31) * 4;

  float acc[8][8];
#pragma unroll
  for (int i = 0; i < 8; ++i)
#pragma unroll
    for (int j = 0; j < 8; ++j) acc[i][j] = 0.f;

  for (int k0 = 0; k0 < K; k0 += 8) {
    float4 av = make_float4(0.f, 0.f, 0.f, 0.f);
    if (row0 + arow < M) {
      int kb = k0 + acol;
      av = *reinterpret_cast<const float4*>(&A[(size_t)(row0 + arow) * K + kb]);
    }
    As[acol + 0][arow] = av.x;
    As[acol + 1][arow] = av.y;
    As[acol + 2][arow] = av.z;
    As[acol + 3][arow] = av.w;
    float4 bv = make_float4(0.f, 0.f, 0.f, 0.f);
    if (k0 + brow < K) {
      bv = *reinterpret_cast<const float4*>(&B[(size_t)(k0 + brow) * N + col0 + bcol]);
    }
    *reinterpret_cast<float4*>(&Bs[brow][bcol]) = bv;
    __syncthreads();
#pragma unroll
    for (int kk = 0; kk < 8; ++kk) {
      float a[8], b[8];
      *reinterpret_cast<float4*>(&a[0]) = *reinterpret_cast<const float4*>(&As[kk][tm]);
      *reinterpret_cast<float4*>(&a[4]) = *reinterpret_cast<const float4*>(&As[kk][tm + 4]);
      *reinterpret_cast<float4*>(&b[0]) = *reinterpret_cast<const float4*>(&Bs[kk][tn]);
      *reinterpret_cast<float4*>(&b[4]) = *reinterpret_cast<const float4*>(&Bs[kk][tn + 4]);
#pragma unroll
      for (int i = 0; i < 8; ++i)
#pragma unroll
        for (int j = 0; j < 8; ++j) acc[i][j] = fmaf(a[i], b[j], acc[i][j]);
    }
    __syncthreads();
  }
#pragma unroll
  for (int i = 0; i < 8; ++i) {
    int r = row0 + tm + i;
    if (r < M) {
#pragma unroll
      for (int j = 0; j < 8; ++j) {
        int c = col0 + tn + j;
        if (c < N) C[(size_t)r * N + c] = acc[i][j];
      }
    }
  }
}

// ---------------------------------------------------------------------------
// x fp32 -> xh, xl bf16 (hi/lo split), same layout.
// ---------------------------------------------------------------------------
__global__ __launch_bounds__(256) void repack_x_hl(const float* __restrict__ x,
                                                   unsigned short* __restrict__ xh,
                                                   unsigned short* __restrict__ xl) {
  int i = (blockIdx.x * 256 + threadIdx.x) * 4;
  float4 v = *reinterpret_cast<const float4*>(&x[i]);
  float f[4] = {v.x, v.y, v.z, v.w};
  unsigned short h[4], l[4];
#pragma unroll
  for (int j = 0; j < 4; ++j) {
    h[j] = f2bf(f[j]);
    l[j] = f2bf(f[j] - bf2f(h[j]));
  }
  *reinterpret_cast<ushort4*>(&xh[i]) = make_ushort4(h[0], h[1], h[2], h[3]);
  *reinterpret_cast<ushort4*>(&xl[i]) = make_ushort4(l[0], l[1], l[2], l[3]);
}

// ---------------------------------------------------------------------------
// W (rows x cols, fp32) -> W^T bf16 hi (and optional lo), (cols x rows).
// ---------------------------------------------------------------------------
__global__ __launch_bounds__(256) void repack_T(const float* __restrict__ W,
                                                unsigned short* __restrict__ hiT,
                                                unsigned short* __restrict__ loT,
                                                int rows, int cols, int has_lo) {
  __shared__ float t[64][65];
  const int k0 = blockIdx.y * 64, n0 = blockIdx.x * 64;
  const int tid = threadIdx.x;
  const int c = tid & 63, rr = tid >> 6;
#pragma unroll
  for (int r = 0; r < 16; ++r) {
    int kr = r * 4 + rr;
    t[kr][c] = W[(size_t)(k0 + kr) * cols + n0 + c];
  }
  __syncthreads();
#pragma unroll
  for (int r = 0; r < 16; ++r) {
    int n = r * 4 + rr;
    float f = t[c][n];
    unsigned short hb = f2bf(f);
    hiT[(size_t)(n0 + n) * rows + k0 + c] = hb;
    if (has_lo) loT[(size_t)(n0 + n) * rows + k0 + c] = f2bf(f - bf2f(hb));
  }
}

// ---------------------------------------------------------------------------
// RoPE applied in-place to q and k.
// ---------------------------------------------------------------------------
__global__ __launch_bounds__(256) void rope_qk(float* __restrict__ q, float* __restrict__ kk) {
  int idx = blockIdx.x * 256 + threadIdx.x;
  if (idx >= S_LEN * NH * (HD / 2)) return;
  int d = idx & 31;
  int sh = idx >> 5;
  int s = sh >> 5;
  float inv = 1.0f / powf(10000.0f, (float)d * (1.0f / 32.0f));
  float fr = (float)s * inv;
  float c = cosf(fr), sn = sinf(fr);
  size_t base = (size_t)sh * HD + d;
  float q1 = q[base], q2 = q[base + 32];
  q[base] = q1 * c - q2 * sn;
  q[base + 32] = q2 * c + q1 * sn;
  float k1 = kk[base], k2 = kk[base + 32];
  kk[base] = k1 * c - k2 * sn;
  kk[base + 32] = k2 * c + k1 * sn;
}

// ---------------------------------------------------------------------------
// Chunk means of k.
// ---------------------------------------------------------------------------
__global__ __launch_bounds__(256) void chunk_mean(const float* __restrict__ k,
                                                  float* __restrict__ kg) {
  int idx = blockIdx.x * 256 + threadIdx.x;
  if (idx >= NCH * NH * HD) return;
  int c = idx / (NH * HD);
  int hd = idx % (NH * HD);
  float sum = 0.f;
  for (int t = 0; t < CS; ++t) sum += k[(size_t)(c * CS + t) * (NH * HD) + hd];
  kg[idx] = sum * (1.0f / CS);
}

// ---------------------------------------------------------------------------
// Gate + top-3-past chunk selection (fp32 — selection must stay exact).
// ---------------------------------------------------------------------------
__global__ __launch_bounds__(256) void gate_topk(const float* __restrict__ q,
                                                 const float* __restrict__ kg,
                                                 int* __restrict__ amask) {
  int wid = threadIdx.x >> 6;
  int lane = threadIdx.x & 63;
  int s = blockIdx.x * 4 + wid;
  int h = blockIdx.y;
  int myc = s >> 8;
  float qd = q[((size_t)s * NH + h) * HD + lane];
  float g[NCH];
#pragma unroll
  for (int c = 0; c < NCH; ++c) {
    float p = qd * kg[((size_t)c * NH + h) * HD + lane];
#pragma unroll
    for (int off = 32; off; off >>= 1) p += __shfl_xor(p, off);
    g[c] = p;
  }
  int chosen = 0;
#pragma unroll
  for (int pick = 0; pick < 3; ++pick) {
    float best = -INFINITY;
    int bi = -1;
#pragma unroll
    for (int c = 0; c < NCH; ++c) {
      if (c < myc && !((chosen >> c) & 1) && g[c] > best) {
        best = g[c];
        bi = c;
      }
    }
    if (bi >= 0) chosen |= (1 << bi);
  }
  int mask = chosen | (1 << myc);
  if (lane == 0) amask[h * S_LEN + s] = mask;
}

// ---------------------------------------------------------------------------
// Repack k fp32 [s][h][d] -> kh bf16 [h][s][d]
// ---------------------------------------------------------------------------
__global__ __launch_bounds__(256) void repack_k(const float* __restrict__ k,
                                                unsigned short* __restrict__ kh) {
  int t = blockIdx.x * 256 + threadIdx.x;
  int d4 = (t & 15) * 4;
  int s = (t >> 4) & (S_LEN - 1);
  int h = t >> 15;
  float4 v = *reinterpret_cast<const float4*>(&k[(((size_t)s * NH + h) * HD + d4)]);
  size_t oi = ((size_t)h * S_LEN + s) * HD + d4;
  *reinterpret_cast<ushort4*>(&kh[oi]) =
      make_ushort4(f2bf(v.x), f2bf(v.y), f2bf(v.z), f2bf(v.w));
}

// ---------------------------------------------------------------------------
// Repack v fp32 [s][h][d] -> vT bf16 [h][d][s]  (LDS transpose)
// ---------------------------------------------------------------------------
__global__ __launch_bounds__(256) void repack_vT(const float* __restrict__ v,
                                                 unsigned short* __restrict__ vT) {
  __shared__ float tile[64][65];
  const int h = blockIdx.y;
  const int sb = blockIdx.x * 64;
  const int tid = threadIdx.x;
#pragma unroll
  for (int r = 0; r < 16; ++r) {
    int row = r * 4 + (tid >> 6);
    int d = tid & 63;
    tile[row][d] = v[((size_t)(sb + row) * NH + h) * HD + d];
  }
  __syncthreads();
#pragma unroll
  for (int r = 0; r < 16; ++r) {
    int d = r * 4 + (tid >> 6);
    int si = tid & 63;
    vT[((size_t)h * HD + d) * S_LEN + sb + si] = f2bf(tile[si][d]);
  }
}

// ---------------------------------------------------------------------------
// MFMA flash attention, split-K across 4 waves per workgroup.
// Grid flattened to 4096; decoded so each XCD (bid&7) owns heads
// {xcd, xcd+8, xcd+16, xcd+24} processed sequentially -> per-XCD K/V
// working set ~512KB (fits 4MB XCD L2), vs round-robin thrash before.
// ---------------------------------------------------------------------------
__global__ __launch_bounds__(256) void attn_mfma(const float* __restrict__ q,
                                                 const unsigned short* __restrict__ kh,
                                                 const unsigned short* __restrict__ vT,
                                                 const int* __restrict__ amask,
                                                 float* __restrict__ o) {
  const int B = blockIdx.x;
  const int xcd = B & 7;
  const int j = B >> 3;
  const int h = xcd + ((j >> 7) << 3);
  const int s0 = (j & 127) << 4;
  const int tid = threadIdx.x;
  const int wid = tid >> 6;
  const int lane = tid & 63;
  const int l15 = lane & 15, g = lane >> 4;
  const int myS = s0 + l15;
  const int myc = s0 >> 8;

  __shared__ float lm[4][16];
  __shared__ float ll[4][16];
  __shared__ float lacc[4][16][64];  // [wave][reg(cb*4+r)][lane]

  // Q B-frag (16x16x32): lane holds Q[row=l15][hd=hf*32+g*8+j]
  const float* qrow = q + ((size_t)myS * NH + h) * HD;
  bf16x8 qf[2];
#pragma unroll
  for (int hf = 0; hf < 2; ++hf)
#pragma unroll
    for (int jj = 0; jj < 8; ++jj) qf[hf][jj] = (short)f2bf(qrow[hf * 32 + g * 8 + jj]);

  int mymask = amask[h * S_LEN + myS];
  int wmask = mymask;
  wmask |= __shfl_xor(wmask, 1);
  wmask |= __shfl_xor(wmask, 2);
  wmask |= __shfl_xor(wmask, 4);
  wmask |= __shfl_xor(wmask, 8);

  float m = -1e30f, lsum = 0.f;
  f32x4 accv[4];
#pragma unroll
  for (int i = 0; i < 4; ++i) accv[i] = (f32x4){0.f, 0.f, 0.f, 0.f};

  const int ktm = (s0 & (CS - 1)) >> 6;
  const unsigned short* khh = kh + (size_t)h * S_LEN * HD;
  const unsigned short* vth = vT + (size_t)h * HD * S_LEN;

  int tcnt = 0;
  for (int c = 0; c <= myc; ++c) {
    if (!((wmask >> c) & 1)) continue;
    const bool lane_on = (mymask >> c) & 1;
    const int nkt = (c == myc) ? (ktm + 1) : 4;
    for (int kt = 0; kt < nkt; ++kt, ++tcnt) {
      if ((tcnt & 3) != wid) continue;
      const int t0 = c * CS + kt * 64;
      const bool diag = (c == myc) && (kt == ktm);

      // Prefetch V B-frags (16x16x16)
      bf16x4 vb[4][4];
#pragma unroll
      for (int st = 0; st < 4; ++st)
#pragma unroll
        for (int cb = 0; cb < 4; ++cb)
          vb[st][cb] = *reinterpret_cast<const bf16x4*>(
              vth + (size_t)(cb * 16 + l15) * S_LEN + t0 + st * 16 + 4 * g);

      // S^T tile: 4 key-subtiles x 2 hd-halves
      float p[16];
      float mt = -1e30f;
#pragma unroll
      for (int st = 0; st < 4; ++st) {
        const size_t krow = (size_t)(t0 + st * 16 + l15) * HD + g * 8;
        bf16x8 a0 = *reinterpret_cast<const bf16x8*>(khh + krow);
        bf16x8 a1 = *reinterpret_cast<const bf16x8*>(khh + krow + 32);
        f32x4 d = (f32x4){0.f, 0.f, 0.f, 0.f};
        d = __builtin_amdgcn_mfma_f32_16x16x32_bf16(a0, qf[0], d, 0, 0, 0);
        d = __builtin_amdgcn_mfma_f32_16x16x32_bf16(a1, qf[1], d, 0, 0, 0);
#pragma unroll
        for (int r = 0; r < 4; ++r) {
          bool ok = lane_on && (!diag || (t0 + st * 16 + 4 * g + r <= myS));
          float sv = ok ? d[r] * 0.125f : -1e30f;
          p[st * 4 + r] = sv;
          mt = fmaxf(mt, sv);
        }
      }
      mt = fmaxf(mt, __shfl_xor(mt, 16));
      mt = fmaxf(mt, __shfl_xor(mt, 32));
      const float mnew = fmaxf(m, mt);
      const float corr = __expf(m - mnew);
      float ps = 0.f;
#pragma unroll
      for (int i = 0; i < 16; ++i) {
        float pv = (p[i] > -1e29f) ? __expf(p[i] - mnew) : 0.f;
        p[i] = pv;
        ps += pv;
      }
      ps += __shfl_xor(ps, 16);
      ps += __shfl_xor(ps, 32);
      lsum = lsum * corr + ps;
      m = mnew;

      // Rescale accumulator (acc rows are q-rows 4g+r; corr lives at lane 4g+r)
#pragma unroll
      for (int r = 0; r < 4; ++r) {
        float cr = __shfl(corr, 4 * g + r);
#pragma unroll
        for (int cb = 0; cb < 4; ++cb) accv[cb][r] *= cr;
      }

      // PV: P fragment (A of 16x16x16) is exactly the S^T output fragment
#pragma unroll
      for (int st = 0; st < 4; ++st) {
        bf16x4 pa;
#pragma unroll
        for (int jj = 0; jj < 4; ++jj) pa[jj] = (short)f2bf(p[st * 4 + jj]);
#pragma unroll
        for (int cb = 0; cb < 4; ++cb)
          accv[cb] = mfma16(pa, vb[st][cb], accv[cb]);
      }
    }
  }

  // ---- store partials to LDS ----
#pragma unroll
  for (int cb = 0; cb < 4; ++cb)
#pragma unroll
    for (int r = 0; r < 4; ++r) lacc[wid][cb * 4 + r][lane] = accv[cb][r];
  if (lane < 16) {
    lm[wid][lane] = m;
    ll[wid][lane] = lsum;
  }
  __syncthreads();

  // ---- merge: wave `wid` produces dim-block cb = wid ----
  float outv[4];
#pragma unroll
  for (int r = 0; r < 4; ++r) {
    const int row = 4 * g + r;
    float m0 = lm[0][row], m1 = lm[1][row], m2 = lm[2][row], m3 = lm[3][row];
    float mt = fmaxf(fmaxf(m0, m1), fmaxf(m2, m3));
    float e0 = __expf(m0 - mt), e1 = __expf(m1 - mt);
    float e2 = __expf(m2 - mt), e3 = __expf(m3 - mt);
    float ltot = ll[0][row] * e0 + ll[1][row] * e1 + ll[2][row] * e2 + ll[3][row] * e3;
    float a = lacc[0][wid * 4 + r][lane] * e0 + lacc[1][wid * 4 + r][lane] * e1 +
              lacc[2][wid * 4 + r][lane] * e2 + lacc[3][wid * 4 + r][lane] * e3;
    outv[r] = a / ltot;
  }
#pragma unroll
  for (int r = 0; r < 4; ++r)
    o[((size_t)(s0 + 4 * g + r) * NH + h) * HD + wid * 16 + l15] = outv[r];
}

// ---------------------------------------------------------------------------
// RMS-norm + sigmoid gate; emits bf16 for the out-proj A-operand.
// ---------------------------------------------------------------------------
__global__ __launch_bounds__(256) void postproc(const float* __restrict__ o,
                                                const float* __restrict__ g,
                                                const float* __restrict__ w,
                                                unsigned short* __restrict__ o2h) {
  int idx = blockIdx.x * 256 + threadIdx.x;
  int lane = threadIdx.x & 63;
  float val = o[idx];
  float ss = val * val;
#pragma unroll
  for (int off = 32; off; off >>= 1) ss += __shfl_xor(ss, off);
  float r = rsqrtf(ss * (1.0f / HD) + 1e-6f);
  float gv = g[idx];
  float sig = 1.0f / (1.0f + expf(-gv));
  o2h[idx] = f2bf(val * r * w[lane] * sig);
}

// ---------------------------------------------------------------------------
extern "C" void kernel_launch(void* const* d_in, const int* in_sizes, int n_in,
                              void* d_out, int out_size, void* d_ws, size_t ws_size,
                              hipStream_t stream) {
  const float* x   = (const float*)d_in[0];
  const float* Wq  = (const float*)d_in[1];
  const float* Wk  = (const float*)d_in[2];
  const float* Wv  = (const float*)d_in[3];
  const float* Wo  = (const float*)d_in[4];
  const float* Wg1 = (const float*)d_in[5];
  const float* Wg2 = (const float*)d_in[6];
  const float* onw = (const float*)d_in[7];
  float* out = (float*)d_out;

  const size_t BIG = (size_t)S_LEN * D_DIM;  // 4M elements
  float* q  = (float*)d_ws;
  float* k  = q + BIG;
  float* v  = k + BIG;
  float* o  = v + BIG;
  float* kg = o + BIG;                        // NCH*NH*HD
  int* amask = (int*)(kg + NCH * NH * HD);    // NH*S
  unsigned short* xh  = (unsigned short*)(amask + NH * S_LEN);
  unsigned short* xl  = xh + BIG;
  unsigned short* whT = xl + BIG;
  unsigned short* wlT = whT + BIG;
  unsigned short* kh  = wlT + BIG;
  unsigned short* vT  = kh + BIG;
  unsigned short* o2h = vT + BIG;

  const dim3 gT(32, 32);
  const int GEMM_GRID = (S_LEN / 64) * (D_DIM / 128);  // 512 blocks
  // Split x into hi/lo bf16
  repack_x_hl<<<(int)(BIG / 4 / 256), 256, 0, stream>>>(x, xh, xl);

  // Q = x@Wq (3-pass hi/lo)
  repack_T<<<gT, 256, 0, stream>>>(Wq, whT, wlT, D_DIM, D_DIM, 1);
  {
    G3 g3{{xh, xh, xl}, {whT, wlT, whT}, 3};
    gemm_bt<<<GEMM_GRID, 256, 0, stream>>>(g3, q, S_LEN, D_DIM, D_DIM);
  }
  // K = x@Wk (3-pass hi/lo)
  repack_T<<<gT, 256, 0, stream>>>(Wk, whT, wlT, D_DIM, D_DIM, 1);
  {
    G3 g3{{xh, xh, xl}, {whT, wlT, whT}, 3};
    gemm_bt<<<GEMM_GRID, 256, 0, stream>>>(g3, k, S_LEN, D_DIM, D_DIM);
  }
  // V = x@Wv (1-pass bf16)
  repack_T<<<gT, 256, 0, stream>>>(Wv, whT, nullptr, D_DIM, D_DIM, 0);
  {
    G3 g3{{xh, xh, xh}, {whT, whT, whT}, 1};
    gemm_bt<<<GEMM_GRID, 256, 0, stream>>>(g3, v, S_LEN, D_DIM, D_DIM);
  }
  // RoPE
  rope_qk<<<S_LEN * NH * (HD / 2) / 256, 256, 0, stream>>>(q, k);
  // Chunk means + gating (fp32)
  chunk_mean<<<(NCH * NH * HD + 255) / 256, 256, 0, stream>>>(k, kg);
  gate_topk<<<dim3(S_LEN / 4, NH), 256, 0, stream>>>(q, kg, amask);
  // Repack for MFMA attention
  repack_k<<<(int)(BIG / 4 / 256), 256, 0, stream>>>(k, kh);
  repack_vT<<<dim3(S_LEN / 64, NH), 256, 0, stream>>>(v, vT);
  // W' = Wg1 @ Wg2 (fp32, K=64) into o; then repack to bf16 T
  sgemm_f32<<<dim3(16, 16), 256, 0, stream>>>(Wg1, Wg2, o, D_DIM, D_DIM, HD);
  repack_T<<<gT, 256, 0, stream>>>(o, whT, nullptr, D_DIM, D_DIM, 0);
  // Attention (overwrites o): 4-wave split-K, head-locality XCD swizzle
  attn_mfma<<<(S_LEN / 16) * NH, 256, 0, stream>>>(q, kh, vT, amask, o);
  // g = x @ W' (1-pass bf16) into k buffer
  {
    G3 g3{{xh, xh, xh}, {whT, whT, whT}, 1};
    gemm_bt<<<GEMM_GRID, 256, 0, stream>>>(g3, k, S_LEN, D_DIM, D_DIM);
  }
  // RMS-norm + sigmoid gate -> bf16
  postproc<<<(int)(BIG / 256), 256, 0, stream>>>(o, k, onw, o2h);
  // out = o2 @ Wo (1-pass bf16)
  repack_T<<<gT, 256, 0, stream>>>(Wo, whT, nullptr, D_DIM, D_DIM, 0);
  {
    G3 g3{{o2h, o2h, o2h}, {whT, whT, whT}, 1};
    gemm_bt<<<GEMM_GRID, 256, 0, stream>>>(g3, out, S_LEN, D_DIM, D_DIM);
  }
}

// Round 9
// 592.827 us; speedup vs baseline: 1.3306x; 1.0053x over previous
//
#include <hip/hip_runtime.h>
#include <hip/hip_bf16.h>
#include <math.h>

#define S_LEN 2048
#define D_DIM 2048
#define NH 32
#define HD 64
#define CS 256
#define NCH 8

typedef __attribute__((ext_vector_type(8))) short bf16x8;
typedef __attribute__((ext_vector_type(4))) short bf16x4;
typedef __attribute__((ext_vector_type(4))) float f32x4;

__device__ __forceinline__ unsigned short f2bf(float f) {
  unsigned int u = __builtin_bit_cast(unsigned int, f);
  unsigned int r = (u + 0x7fffu + ((u >> 16) & 1u)) >> 16;
  return (unsigned short)r;
}
__device__ __forceinline__ float bf2f(unsigned short b) {
  unsigned int u = ((unsigned int)b) << 16;
  return __builtin_bit_cast(float, u);
}

__device__ __forceinline__ f32x4 mfma16(bf16x4 a, bf16x4 b, f32x4 c) {
#if __has_builtin(__builtin_amdgcn_mfma_f32_16x16x16_bf16)
  return __builtin_amdgcn_mfma_f32_16x16x16_bf16(a, b, c, 0, 0, 0);
#elif __has_builtin(__builtin_amdgcn_mfma_f32_16x16x16bf16_1k)
  return __builtin_amdgcn_mfma_f32_16x16x16bf16_1k(a, b, c, 0, 0, 0);
#else
  asm("v_mfma_f32_16x16x16_bf16 %0, %1, %2, %0" : "+v"(c) : "v"(a), "v"(b));
  return c;
#endif
}

__device__ __forceinline__ void gload16(const void* gp, void* lp) {
  __builtin_amdgcn_global_load_lds(
      (const __attribute__((address_space(1))) unsigned int*)gp,
      (__attribute__((address_space(3))) unsigned int*)lp, 16, 0, 0);
}

// ---------------------------------------------------------------------------
// bf16 MFMA GEMM: C(MxN fp32) = sum_p A_p(MxK bf16) @ B_p^T(NxK bf16).
// 64x128 tile, BK=64, 4 waves.
// ---------------------------------------------------------------------------
struct G3 {
  const unsigned short* A[3];
  const unsigned short* B[3];
  int np;
};

__global__ __launch_bounds__(256) void gemm_bt(G3 g, float* __restrict__ C,
                                               int M, int N, int K) {
  __shared__ __align__(16) unsigned short Als[64 * 64];
  __shared__ __align__(16) unsigned short Bls[128 * 64];
  const int tid = threadIdx.x;
  const int wid = tid >> 6, lane = tid & 63;
  const int l15 = lane & 15, l4 = lane >> 4;
  const int wr = wid >> 1, wc = wid & 1;
  const int nbx = N >> 7;
  int bid = blockIdx.x;
  const int nwg = gridDim.x;
  if ((nwg & 7) == 0) {  // bijective XCD swizzle
    int q = nwg >> 3;
    bid = (bid & 7) * q + (bid >> 3);
  }
  const int row0 = (bid / nbx) << 6;
  const int col0 = (bid % nbx) << 7;

  f32x4 acc[2][4];
#pragma unroll
  for (int m = 0; m < 2; ++m)
#pragma unroll
    for (int n = 0; n < 4; ++n) acc[m][n] = (f32x4){0.f, 0.f, 0.f, 0.f};

  for (int p = 0; p < g.np; ++p) {
    const unsigned short* Ap = g.A[p];
    const unsigned short* Bp = g.B[p];
    for (int kt = 0; kt < K; kt += 64) {
      __syncthreads();
#pragma unroll
      for (int i = 0; i < 2; ++i) {
        const int Lb = i * 4096 + wid * 1024;
        const int L = Lb + lane * 16;
        const int row = L >> 7;
        const int s = (L >> 4) & 7;
        const int cofs = (s ^ (row & 7)) << 3;
        gload16(Ap + (size_t)(row0 + row) * K + kt + cofs, (char*)Als + Lb);
      }
#pragma unroll
      for (int i = 0; i < 4; ++i) {
        const int Lb = i * 4096 + wid * 1024;
        const int L = Lb + lane * 16;
        const int row = L >> 7;
        const int s = (L >> 4) & 7;
        const int cofs = (s ^ (row & 7)) << 3;
        gload16(Bp + (size_t)(col0 + row) * K + kt + cofs, (char*)Bls + Lb);
      }
      asm volatile("s_waitcnt vmcnt(0)" ::: "memory");
      __syncthreads();
#pragma unroll
      for (int ks = 0; ks < 2; ++ks) {
        bf16x8 af[2], bfr[4];
#pragma unroll
        for (int m = 0; m < 2; ++m) {
          int row = wr * 32 + m * 16 + l15;
          int s = (ks * 4 + l4) ^ (row & 7);
          af[m] = *reinterpret_cast<const bf16x8*>(&Als[row * 64 + s * 8]);
        }
#pragma unroll
        for (int n = 0; n < 4; ++n) {
          int col = wc * 64 + n * 16 + l15;
          int s = (ks * 4 + l4) ^ (col & 7);
          bfr[n] = *reinterpret_cast<const bf16x8*>(&Bls[col * 64 + s * 8]);
        }
#pragma unroll
        for (int m = 0; m < 2; ++m)
#pragma unroll
          for (int n = 0; n < 4; ++n)
            acc[m][n] = __builtin_amdgcn_mfma_f32_16x16x32_bf16(af[m], bfr[n], acc[m][n], 0, 0, 0);
      }
    }
  }

#pragma unroll
  for (int m = 0; m < 2; ++m)
#pragma unroll
    for (int n = 0; n < 4; ++n)
#pragma unroll
      for (int r = 0; r < 4; ++r)
        C[(size_t)(row0 + wr * 32 + m * 16 + l4 * 4 + r) * N + col0 + wc * 64 + n * 16 + l15] =
            acc[m][n][r];
}

// ---------------------------------------------------------------------------
// fp32 SGEMM (kept only for W' = Wg1 @ Wg2, K=64).
// ---------------------------------------------------------------------------
__global__ __launch_bounds__(256) void sgemm_f32(const float* __restrict__ A,
                                                 const float* __restrict__ B,
                                                 float* __restrict__ C,
                                                 int M, int N, int K) {
  __shared__ float As[8][128];
  __shared__ float Bs[8][128];
  const int tid = threadIdx.x;
  const int row0 = blockIdx.y * 128;
  const int col0 = blockIdx.x * 128;
  const int tm = (tid / 16) * 8;
  const int tn = (tid % 16) * 8;
  const int arow = tid >> 1;
  const int acol = (tid & 1) * 4;
  const int brow = tid >> 5;
  const int bcol = (tid & 31) * 4;

  float acc[8][8];
#pragma unroll
  for (int i = 0; i < 8; ++i)
#pragma unroll
    for (int j = 0; j < 8; ++j) acc[i][j] = 0.f;

  for (int k0 = 0; k0 < K; k0 += 8) {
    float4 av = make_float4(0.f, 0.f, 0.f, 0.f);
    if (row0 + arow < M) {
      int kb = k0 + acol;
      av = *reinterpret_cast<const float4*>(&A[(size_t)(row0 + arow) * K + kb]);
    }
    As[acol + 0][arow] = av.x;
    As[acol + 1][arow] = av.y;
    As[acol + 2][arow] = av.z;
    As[acol + 3][arow] = av.w;
    float4 bv = make_float4(0.f, 0.f, 0.f, 0.f);
    if (k0 + brow < K) {
      bv = *reinterpret_cast<const float4*>(&B[(size_t)(k0 + brow) * N + col0 + bcol]);
    }
    *reinterpret_cast<float4*>(&Bs[brow][bcol]) = bv;
    __syncthreads();
#pragma unroll
    for (int kk = 0; kk < 8; ++kk) {
      float a[8], b[8];
      *reinterpret_cast<float4*>(&a[0]) = *reinterpret_cast<const float4*>(&As[kk][tm]);
      *reinterpret_cast<float4*>(&a[4]) = *reinterpret_cast<const float4*>(&As[kk][tm + 4]);
      *reinterpret_cast<float4*>(&b[0]) = *reinterpret_cast<const float4*>(&Bs[kk][tn]);
      *reinterpret_cast<float4*>(&b[4]) = *reinterpret_cast<const float4*>(&Bs[kk][tn + 4]);
#pragma unroll
      for (int i = 0; i < 8; ++i)
#pragma unroll
        for (int j = 0; j < 8; ++j) acc[i][j] = fmaf(a[i], b[j], acc[i][j]);
    }
    __syncthreads();
  }
#pragma unroll
  for (int i = 0; i < 8; ++i) {
    int r = row0 + tm + i;
    if (r < M) {
#pragma unroll
      for (int j = 0; j < 8; ++j) {
        int c = col0 + tn + j;
        if (c < N) C[(size_t)r * N + c] = acc[i][j];
      }
    }
  }
}

// ---------------------------------------------------------------------------
// x fp32 -> xh, xl bf16 (hi/lo split), same layout.
// ---------------------------------------------------------------------------
__global__ __launch_bounds__(256) void repack_x_hl(const float* __restrict__ x,
                                                   unsigned short* __restrict__ xh,
                                                   unsigned short* __restrict__ xl) {
  int i = (blockIdx.x * 256 + threadIdx.x) * 4;
  float4 v = *reinterpret_cast<const float4*>(&x[i]);
  float f[4] = {v.x, v.y, v.z, v.w};
  unsigned short h[4], l[4];
#pragma unroll
  for (int j = 0; j < 4; ++j) {
    h[j] = f2bf(f[j]);
    l[j] = f2bf(f[j] - bf2f(h[j]));
  }
  *reinterpret_cast<ushort4*>(&xh[i]) = make_ushort4(h[0], h[1], h[2], h[3]);
  *reinterpret_cast<ushort4*>(&xl[i]) = make_ushort4(l[0], l[1], l[2], l[3]);
}

// ---------------------------------------------------------------------------
// W (rows x cols, fp32) -> W^T bf16 hi (and optional lo), (cols x rows).
// ---------------------------------------------------------------------------
__global__ __launch_bounds__(256) void repack_T(const float* __restrict__ W,
                                                unsigned short* __restrict__ hiT,
                                                unsigned short* __restrict__ loT,
                                                int rows, int cols, int has_lo) {
  __shared__ float t[64][65];
  const int k0 = blockIdx.y * 64, n0 = blockIdx.x * 64;
  const int tid = threadIdx.x;
  const int c = tid & 63, rr = tid >> 6;
#pragma unroll
  for (int r = 0; r < 16; ++r) {
    int kr = r * 4 + rr;
    t[kr][c] = W[(size_t)(k0 + kr) * cols + n0 + c];
  }
  __syncthreads();
#pragma unroll
  for (int r = 0; r < 16; ++r) {
    int n = r * 4 + rr;
    float f = t[c][n];
    unsigned short hb = f2bf(f);
    hiT[(size_t)(n0 + n) * rows + k0 + c] = hb;
    if (has_lo) loT[(size_t)(n0 + n) * rows + k0 + c] = f2bf(f - bf2f(hb));
  }
}

// ---------------------------------------------------------------------------
// RoPE applied in-place to q and k.
// ---------------------------------------------------------------------------
__global__ __launch_bounds__(256) void rope_qk(float* __restrict__ q, float* __restrict__ kk) {
  int idx = blockIdx.x * 256 + threadIdx.x;
  if (idx >= S_LEN * NH * (HD / 2)) return;
  int d = idx & 31;
  int sh = idx >> 5;
  int s = sh >> 5;
  float inv = 1.0f / powf(10000.0f, (float)d * (1.0f / 32.0f));
  float fr = (float)s * inv;
  float c = cosf(fr), sn = sinf(fr);
  size_t base = (size_t)sh * HD + d;
  float q1 = q[base], q2 = q[base + 32];
  q[base] = q1 * c - q2 * sn;
  q[base + 32] = q2 * c + q1 * sn;
  float k1 = kk[base], k2 = kk[base + 32];
  kk[base] = k1 * c - k2 * sn;
  kk[base + 32] = k2 * c + k1 * sn;
}

// ---------------------------------------------------------------------------
// Chunk means of k.
// ---------------------------------------------------------------------------
__global__ __launch_bounds__(256) void chunk_mean(const float* __restrict__ k,
                                                  float* __restrict__ kg) {
  int idx = blockIdx.x * 256 + threadIdx.x;
  if (idx >= NCH * NH * HD) return;
  int c = idx / (NH * HD);
  int hd = idx % (NH * HD);
  float sum = 0.f;
  for (int t = 0; t < CS; ++t) sum += k[(size_t)(c * CS + t) * (NH * HD) + hd];
  kg[idx] = sum * (1.0f / CS);
}

// ---------------------------------------------------------------------------
// Gate + top-3-past chunk selection (fp32 — selection must stay exact).
// ---------------------------------------------------------------------------
__global__ __launch_bounds__(256) void gate_topk(const float* __restrict__ q,
                                                 const float* __restrict__ kg,
                                                 int* __restrict__ amask) {
  int wid = threadIdx.x >> 6;
  int lane = threadIdx.x & 63;
  int s = blockIdx.x * 4 + wid;
  int h = blockIdx.y;
  int myc = s >> 8;
  float qd = q[((size_t)s * NH + h) * HD + lane];
  float g[NCH];
#pragma unroll
  for (int c = 0; c < NCH; ++c) {
    float p = qd * kg[((size_t)c * NH + h) * HD + lane];
#pragma unroll
    for (int off = 32; off; off >>= 1) p += __shfl_xor(p, off);
    g[c] = p;
  }
  int chosen = 0;
#pragma unroll
  for (int pick = 0; pick < 3; ++pick) {
    float best = -INFINITY;
    int bi = -1;
#pragma unroll
    for (int c = 0; c < NCH; ++c) {
      if (c < myc && !((chosen >> c) & 1) && g[c] > best) {
        best = g[c];
        bi = c;
      }
    }
    if (bi >= 0) chosen |= (1 << bi);
  }
  int mask = chosen | (1 << myc);
  if (lane == 0) amask[h * S_LEN + s] = mask;
}

// ---------------------------------------------------------------------------
// Repack k fp32 [s][h][d] -> kh bf16 [h][s][d]
// ---------------------------------------------------------------------------
__global__ __launch_bounds__(256) void repack_k(const float* __restrict__ k,
                                                unsigned short* __restrict__ kh) {
  int t = blockIdx.x * 256 + threadIdx.x;
  int d4 = (t & 15) * 4;
  int s = (t >> 4) & (S_LEN - 1);
  int h = t >> 15;
  float4 v = *reinterpret_cast<const float4*>(&k[(((size_t)s * NH + h) * HD + d4)]);
  size_t oi = ((size_t)h * S_LEN + s) * HD + d4;
  *reinterpret_cast<ushort4*>(&kh[oi]) =
      make_ushort4(f2bf(v.x), f2bf(v.y), f2bf(v.z), f2bf(v.w));
}

// ---------------------------------------------------------------------------
// Repack v fp32 [s][h][d] -> vT bf16 [h][d][s]  (LDS transpose)
// ---------------------------------------------------------------------------
__global__ __launch_bounds__(256) void repack_vT(const float* __restrict__ v,
                                                 unsigned short* __restrict__ vT) {
  __shared__ float tile[64][65];
  const int h = blockIdx.y;
  const int sb = blockIdx.x * 64;
  const int tid = threadIdx.x;
#pragma unroll
  for (int r = 0; r < 16; ++r) {
    int row = r * 4 + (tid >> 6);
    int d = tid & 63;
    tile[row][d] = v[((size_t)(sb + row) * NH + h) * HD + d];
  }
  __syncthreads();
#pragma unroll
  for (int r = 0; r < 16; ++r) {
    int d = r * 4 + (tid >> 6);
    int si = tid & 63;
    vT[((size_t)h * HD + d) * S_LEN + sb + si] = f2bf(tile[si][d]);
  }
}

// ---------------------------------------------------------------------------
// MFMA flash attention, split-K across 4 waves, pipelined K loads.
// STRUCTURE (R8, verified): arithmetic tile decoder + K-register prefetch.
// NUMERICS (R7, known-good): m=-1e30, unconditional rescale, ternary mask,
// guarded exp, f2bf packing. Scale folded into Q (exact: bf16(q)*2^-3).
// ---------------------------------------------------------------------------
__global__ __launch_bounds__(256) void attn_mfma(const float* __restrict__ q,
                                                 const unsigned short* __restrict__ kh,
                                                 const unsigned short* __restrict__ vT,
                                                 const int* __restrict__ amask,
                                                 float* __restrict__ o) {
  const int B = blockIdx.x;
  const int xcd = B & 7;
  const int jb = B >> 3;
  const int h = xcd + ((jb >> 7) << 3);
  const int s0 = (jb & 127) << 4;
  const int tid = threadIdx.x;
  const int wid = tid >> 6;
  const int lane = tid & 63;
  const int l15 = lane & 15, g = lane >> 4;
  const int myS = s0 + l15;
  const int myc = s0 >> 8;
  const int ktm = (s0 & (CS - 1)) >> 6;

  __shared__ float lm[4][16];
  __shared__ float ll[4][16];
  __shared__ float lacc[4][16][64];

  // Q B-frag, scale 1/8 folded (exact for pow2), f2bf packing
  const float* qrow = q + ((size_t)myS * NH + h) * HD;
  bf16x8 qf[2];
#pragma unroll
  for (int hf = 0; hf < 2; ++hf)
#pragma unroll
    for (int jj = 0; jj < 8; ++jj)
      qf[hf][jj] = (short)f2bf(qrow[hf * 32 + g * 8 + jj] * 0.125f);

  int mymask = amask[h * S_LEN + myS];
  int wmask = mymask;
  wmask |= __shfl_xor(wmask, 1);
  wmask |= __shfl_xor(wmask, 2);
  wmask |= __shfl_xor(wmask, 4);
  wmask |= __shfl_xor(wmask, 8);
  const int pmask = wmask & ~(1 << myc);
  const int ntot = (ktm + 1) + 4 * __popc(pmask);

  // j -> (t0 | lane_on<<16). Self-chunk tiles first, then past chunks.
  auto DEC = [&](int j) -> int {
    if (j <= ktm) return ((s0 & ~255) + (j << 6)) | (1 << 16);
    int jj = j - ktm - 1;
    int mm = pmask;
    int drop = jj >> 2;
    for (int b = 0; b < drop; ++b) mm &= mm - 1;
    int c = __ffs(mm) - 1;
    return ((c << 8) + ((jj & 3) << 6)) | (((mymask >> c) & 1) << 16);
  };

  const unsigned short* khh = kh + (size_t)h * S_LEN * HD;
  const unsigned short* vth = vT + (size_t)h * HD * S_LEN;

  bf16x8 kr[4][2];
  auto LOADK = [&](int t0) {
#pragma unroll
    for (int st = 0; st < 4; ++st) {
      const unsigned short* kp = khh + (size_t)(t0 + st * 16 + l15) * HD + g * 8;
      kr[st][0] = *reinterpret_cast<const bf16x8*>(kp);
      kr[st][1] = *reinterpret_cast<const bf16x8*>(kp + 32);
    }
  };

  float m = -1e30f, lsum = 0.f;
  f32x4 accv[4];
#pragma unroll
  for (int i = 0; i < 4; ++i) accv[i] = (f32x4){0.f, 0.f, 0.f, 0.f};

  if (wid < ntot) LOADK(DEC(wid) & 0xFFFF);

#pragma unroll
  for (int i = 0; i < 8; ++i) {
    const int j = wid + (i << 2);
    if (j < ntot) {
      const int ent = DEC(j);
      const int t0 = ent & 0xFFFF;
      const bool lane_on = (ent >> 16) != 0;
      const bool diag = (j == ktm);

      // V B-frags for this tile (issued early; consumed after softmax)
      bf16x4 vb[4][4];
#pragma unroll
      for (int st = 0; st < 4; ++st)
#pragma unroll
        for (int cb = 0; cb < 4; ++cb)
          vb[st][cb] = *reinterpret_cast<const bf16x4*>(
              vth + (size_t)(cb * 16 + l15) * S_LEN + t0 + st * 16 + 4 * g);

      // QK^T (scale pre-folded into qf); R7-exact masking
      float p[16];
      __builtin_amdgcn_s_setprio(1);
#pragma unroll
      for (int st = 0; st < 4; ++st) {
        f32x4 d = (f32x4){0.f, 0.f, 0.f, 0.f};
        d = __builtin_amdgcn_mfma_f32_16x16x32_bf16(kr[st][0], qf[0], d, 0, 0, 0);
        d = __builtin_amdgcn_mfma_f32_16x16x32_bf16(kr[st][1], qf[1], d, 0, 0, 0);
#pragma unroll
        for (int r = 0; r < 4; ++r) {
          bool ok = lane_on && (!diag || (t0 + st * 16 + 4 * g + r <= myS));
          p[st * 4 + r] = ok ? d[r] : -1e30f;
        }
      }
      __builtin_amdgcn_s_setprio(0);

      // Prefetch next tile's K into the same regs; latency hides under
      // softmax+PV below.
      if (j + 4 < ntot) LOADK(DEC(j + 4) & 0xFFFF);

      // Row max (4-lane groups share a row via xor 16/32)
      float mt = -1e30f;
#pragma unroll
      for (int ii = 0; ii < 16; ++ii) mt = fmaxf(mt, p[ii]);
      mt = fmaxf(mt, __shfl_xor(mt, 16));
      mt = fmaxf(mt, __shfl_xor(mt, 32));

      const float mnew = fmaxf(m, mt);
      const float corr = __expf(m - mnew);
      float ps = 0.f;
#pragma unroll
      for (int ii = 0; ii < 16; ++ii) {
        float pv = (p[ii] > -1e29f) ? __expf(p[ii] - mnew) : 0.f;
        p[ii] = pv;
        ps += pv;
      }
      ps += __shfl_xor(ps, 16);
      ps += __shfl_xor(ps, 32);
      lsum = lsum * corr + ps;
      m = mnew;

      // Rescale accumulator (acc rows are q-rows 4g+r; corr lives at lane 4g+r)
#pragma unroll
      for (int r = 0; r < 4; ++r) {
        float cr = __shfl(corr, 4 * g + r);
#pragma unroll
        for (int cb = 0; cb < 4; ++cb) accv[cb][r] *= cr;
      }

      // PV: P fragment (A of 16x16x16) is exactly the S^T output fragment
      __builtin_amdgcn_s_setprio(1);
#pragma unroll
      for (int st = 0; st < 4; ++st) {
        bf16x4 pa;
#pragma unroll
        for (int jj = 0; jj < 4; ++jj) pa[jj] = (short)f2bf(p[st * 4 + jj]);
#pragma unroll
        for (int cb = 0; cb < 4; ++cb)
          accv[cb] = mfma16(pa, vb[st][cb], accv[cb]);
      }
      __builtin_amdgcn_s_setprio(0);
    }
  }

  // ---- store partials to LDS ----
#pragma unroll
  for (int cb = 0; cb < 4; ++cb)
#pragma unroll
    for (int r = 0; r < 4; ++r) lacc[wid][cb * 4 + r][lane] = accv[cb][r];
  if (lane < 16) {
    lm[wid][lane] = m;
    ll[wid][lane] = lsum;
  }
  __syncthreads();

  // ---- merge: wave `wid` produces dim-block cb = wid ----
  float outv[4];
#pragma unroll
  for (int r = 0; r < 4; ++r) {
    const int row = 4 * g + r;
    float m0 = lm[0][row], m1 = lm[1][row], m2 = lm[2][row], m3 = lm[3][row];
    float mt = fmaxf(fmaxf(m0, m1), fmaxf(m2, m3));
    float e0 = __expf(m0 - mt), e1 = __expf(m1 - mt);
    float e2 = __expf(m2 - mt), e3 = __expf(m3 - mt);
    float ltot = ll[0][row] * e0 + ll[1][row] * e1 + ll[2][row] * e2 + ll[3][row] * e3;
    float a = lacc[0][wid * 4 + r][lane] * e0 + lacc[1][wid * 4 + r][lane] * e1 +
              lacc[2][wid * 4 + r][lane] * e2 + lacc[3][wid * 4 + r][lane] * e3;
    outv[r] = a / ltot;
  }
#pragma unroll
  for (int r = 0; r < 4; ++r)
    o[((size_t)(s0 + 4 * g + r) * NH + h) * HD + wid * 16 + l15] = outv[r];
}

// ---------------------------------------------------------------------------
// RMS-norm + sigmoid gate; emits bf16 for the out-proj A-operand.
// ---------------------------------------------------------------------------
__global__ __launch_bounds__(256) void postproc(const float* __restrict__ o,
                                                const float* __restrict__ g,
                                                const float* __restrict__ w,
                                                unsigned short* __restrict__ o2h) {
  int idx = blockIdx.x * 256 + threadIdx.x;
  int lane = threadIdx.x & 63;
  float val = o[idx];
  float ss = val * val;
#pragma unroll
  for (int off = 32; off; off >>= 1) ss += __shfl_xor(ss, off);
  float r = rsqrtf(ss * (1.0f / HD) + 1e-6f);
  float gv = g[idx];
  float sig = 1.0f / (1.0f + expf(-gv));
  o2h[idx] = f2bf(val * r * w[lane] * sig);
}

// ---------------------------------------------------------------------------
extern "C" void kernel_launch(void* const* d_in, const int* in_sizes, int n_in,
                              void* d_out, int out_size, void* d_ws, size_t ws_size,
                              hipStream_t stream) {
  const float* x   = (const float*)d_in[0];
  const float* Wq  = (const float*)d_in[1];
  const float* Wk  = (const float*)d_in[2];
  const float* Wv  = (const float*)d_in[3];
  const float* Wo  = (const float*)d_in[4];
  const float* Wg1 = (const float*)d_in[5];
  const float* Wg2 = (const float*)d_in[6];
  const float* onw = (const float*)d_in[7];
  float* out = (float*)d_out;

  const size_t BIG = (size_t)S_LEN * D_DIM;  // 4M elements
  float* q  = (float*)d_ws;
  float* k  = q + BIG;
  float* v  = k + BIG;
  float* o  = v + BIG;
  float* kg = o + BIG;                        // NCH*NH*HD
  int* amask = (int*)(kg + NCH * NH * HD);    // NH*S
  unsigned short* xh  = (unsigned short*)(amask + NH * S_LEN);
  unsigned short* xl  = xh + BIG;
  unsigned short* whT = xl + BIG;
  unsigned short* wlT = whT + BIG;
  unsigned short* kh  = wlT + BIG;
  unsigned short* vT  = kh + BIG;
  unsigned short* o2h = vT + BIG;

  const dim3 gT(32, 32);
  const int GEMM_GRID = (S_LEN / 64) * (D_DIM / 128);  // 512 blocks
  // Split x into hi/lo bf16
  repack_x_hl<<<(int)(BIG / 4 / 256), 256, 0, stream>>>(x, xh, xl);

  // Q = x@Wq (3-pass hi/lo)
  repack_T<<<gT, 256, 0, stream>>>(Wq, whT, wlT, D_DIM, D_DIM, 1);
  {
    G3 g3{{xh, xh, xl}, {whT, wlT, whT}, 3};
    gemm_bt<<<GEMM_GRID, 256, 0, stream>>>(g3, q, S_LEN, D_DIM, D_DIM);
  }
  // K = x@Wk (3-pass hi/lo)
  repack_T<<<gT, 256, 0, stream>>>(Wk, whT, wlT, D_DIM, D_DIM, 1);
  {
    G3 g3{{xh, xh, xl}, {whT, wlT, whT}, 3};
    gemm_bt<<<GEMM_GRID, 256, 0, stream>>>(g3, k, S_LEN, D_DIM, D_DIM);
  }
  // V = x@Wv (1-pass bf16)
  repack_T<<<gT, 256, 0, stream>>>(Wv, whT, nullptr, D_DIM, D_DIM, 0);
  {
    G3 g3{{xh, xh, xh}, {whT, whT, whT}, 1};
    gemm_bt<<<GEMM_GRID, 256, 0, stream>>>(g3, v, S_LEN, D_DIM, D_DIM);
  }
  // RoPE
  rope_qk<<<S_LEN * NH * (HD / 2) / 256, 256, 0, stream>>>(q, k);
  // Chunk means + gating (fp32)
  chunk_mean<<<(NCH * NH * HD + 255) / 256, 256, 0, stream>>>(k, kg);
  gate_topk<<<dim3(S_LEN / 4, NH), 256, 0, stream>>>(q, kg, amask);
  // Repack for MFMA attention
  repack_k<<<(int)(BIG / 4 / 256), 256, 0, stream>>>(k, kh);
  repack_vT<<<dim3(S_LEN / 64, NH), 256, 0, stream>>>(v, vT);
  // W' = Wg1 @ Wg2 (fp32, K=64) into o; then repack to bf16 T
  sgemm_f32<<<dim3(16, 16), 256, 0, stream>>>(Wg1, Wg2, o, D_DIM, D_DIM, HD);
  repack_T<<<gT, 256, 0, stream>>>(o, whT, nullptr, D_DIM, D_DIM, 0);
  // Attention (overwrites o): 4-wave split-K, head-locality XCD swizzle
  attn_mfma<<<(S_LEN / 16) * NH, 256, 0, stream>>>(q, kh, vT, amask, o);
  // g = x @ W' (1-pass bf16) into k buffer
  {
    G3 g3{{xh, xh, xh}, {whT, whT, whT}, 1};
    gemm_bt<<<GEMM_GRID, 256, 0, stream>>>(g3, k, S_LEN, D_DIM, D_DIM);
  }
  // RMS-norm + sigmoid gate -> bf16
  postproc<<<(int)(BIG / 256), 256, 0, stream>>>(o, k, onw, o2h);
  // out = o2 @ Wo (1-pass bf16)
  repack_T<<<gT, 256, 0, stream>>>(Wo, whT, nullptr, D_DIM, D_DIM, 0);
  {
    G3 g3{{o2h, o2h, o2h}, {whT, whT, whT}, 1};
    gemm_bt<<<GEMM_GRID, 256, 0, stream>>>(g3, out, S_LEN, D_DIM, D_DIM);
  }
}